// Round 6
// baseline (1245.072 us; speedup 1.0000x reference)
//
#include <hip/hip_runtime.h>
#include <hip/hip_bf16.h>
#include <hip/hip_cooperative_groups.h>

namespace cg = cooperative_groups;

#define TOKENS 8192
#define DM 512
#define NE 8
#define HID 1024
#define NSLOT (TOKENS * 2)
#define NB 32          // token blocks for hist/build (256 tokens each)

#define BM 128
#define BN 64
#define BK 64
#define BN2 128        // gemm2 N-tile
#define MAXTILE 136    // 8 * 17, > sum ceil(counts[e]/BM) worst case (135)

#define GRID 1024      // persistent blocks: 4/CU guaranteed by launch_bounds(256,4) + 32KB LDS

typedef __bf16 bf16x8 __attribute__((ext_vector_type(8)));
typedef float floatx4 __attribute__((ext_vector_type(4)));
typedef unsigned short u16x8 __attribute__((ext_vector_type(8)));

__device__ __forceinline__ unsigned short f2bf(float f) {
    union { float f; unsigned u; } c; c.f = f;
    unsigned u = c.u;
    u += 0x7fffu + ((u >> 16) & 1u);   // RNE
    return (unsigned short)(u >> 16);
}

// async global->LDS, 16B per lane, LDS dest = wave-uniform base + lane*16
__device__ __forceinline__ void load16_lds(const void* g, void* l) {
    __builtin_amdgcn_global_load_lds(
        (const __attribute__((address_space(1))) unsigned int*)g,
        (__attribute__((address_space(3))) unsigned int*)l, 16, 0, 0);
}

// 32 KB shared-memory union — one allocation reused by every phase
union Smem {
    float cvt[64][65];                                                        // prep/cvt (16.6 KB)
    struct { unsigned short As[BM * BK], B1s[BN * BK], B3s[BN * BK]; } g1;    // gemm1 (32 KB)
    struct { unsigned short As[BM * BK], Bs[BN2 * BK]; } g2;                  // gemm2 (32 KB)
    struct { int h[NE]; int cnt[NE]; int cur[NE]; } s;                        // hist/build
};

// map compact tile id gy -> (expert e, tile mt); returns false past the end
__device__ __forceinline__ bool tile_lookup(const int* counts, const int* offsets, int gy,
                                            int& e, int& mt, int& cnt, int& off) {
    int bacc = 0;
    #pragma unroll
    for (int ee = 0; ee < NE; ee++) {
        int c = counts[ee];
        int ntl = (c + BM - 1) >> 7;
        if (gy < bacc + ntl) { e = ee; mt = gy - bacc; cnt = c; off = offsets[ee]; return true; }
        bacc += ntl;
    }
    return false;
}

// ---------------- GEMM1 tile body (proven ~723 TF structure) ----------------
__device__ __forceinline__ void gemm1_tile(
    int lid, Smem& sm,
    const unsigned short* __restrict__ xb, const unsigned short* __restrict__ w1t,
    const unsigned short* __restrict__ w3t, unsigned short* __restrict__ Hb,
    const int* __restrict__ rows, const int* __restrict__ counts,
    const int* __restrict__ offsets) {
    const int xcd = lid & 7;
    const int j = lid >> 3;
    const int gy = xcd * (MAXTILE / 8) + (j >> 4);
    const int nt = j & 15;
    int e, mt, cnt, off;
    if (!tile_lookup(counts, offsets, gy, e, mt, cnt, off)) return;

    unsigned short* As  = sm.g1.As;
    unsigned short* B1s = sm.g1.B1s;
    unsigned short* B3s = sm.g1.B3s;

    const int tid = threadIdx.x;
    const int lane = tid & 63, wave = tid >> 6;
    const int lrow8 = lane >> 3;
    const int lchunk = (lane & 7) ^ lrow8;

    const unsigned short* a_g[4];
    #pragma unroll
    for (int i = 0; i < 4; i++) {
        int r = (wave * 4 + i) * 8 + lrow8;
        int gr = mt * BM + r;
        int tok = rows[off + (gr < cnt ? gr : 0)];
        a_g[i] = xb + (size_t)tok * DM + lchunk * 8;
    }
    const unsigned short* b1_g[2]; const unsigned short* b3_g[2];
    #pragma unroll
    for (int i = 0; i < 2; i++) {
        int r = (wave * 2 + i) * 8 + lrow8;
        b1_g[i] = w1t + ((size_t)e * HID + nt * BN + r) * DM + lchunk * 8;
        b3_g[i] = w3t + ((size_t)e * HID + nt * BN + r) * DM + lchunk * 8;
    }

    const int l15 = lane & 15, quad = lane >> 4;
    const int sw = l15 & 7;

    floatx4 acc1[2][4], acc3[2][4];
    #pragma unroll
    for (int i = 0; i < 2; i++)
        #pragma unroll
        for (int j2 = 0; j2 < 4; j2++) {
            acc1[i][j2] = (floatx4){0.f, 0.f, 0.f, 0.f};
            acc3[i][j2] = (floatx4){0.f, 0.f, 0.f, 0.f};
        }

    __syncthreads();   // LDS free from previous tile/phase

    auto stage = [&](int k0) {
        #pragma unroll
        for (int i = 0; i < 4; i++) load16_lds(a_g[i] + k0, &As[(wave * 4 + i) * 512]);
        #pragma unroll
        for (int i = 0; i < 2; i++) {
            load16_lds(b1_g[i] + k0, &B1s[(wave * 2 + i) * 512]);
            load16_lds(b3_g[i] + k0, &B3s[(wave * 2 + i) * 512]);
        }
    };
    auto compute = [&]() {
        #pragma unroll
        for (int kk = 0; kk < 2; kk++) {
            const int qc = kk * 4 + quad;
            const int ch = (qc ^ sw) << 3;
            bf16x8 af[2], b1f[4], b3f[4];
            #pragma unroll
            for (int mi = 0; mi < 2; mi++)
                af[mi] = *(const bf16x8*)(&As[(wave * 32 + mi * 16 + l15) * 64 + ch]);
            #pragma unroll
            for (int ni = 0; ni < 4; ni++) {
                b1f[ni] = *(const bf16x8*)(&B1s[(ni * 16 + l15) * 64 + ch]);
                b3f[ni] = *(const bf16x8*)(&B3s[(ni * 16 + l15) * 64 + ch]);
            }
            #pragma unroll
            for (int mi = 0; mi < 2; mi++)
                #pragma unroll
                for (int ni = 0; ni < 4; ni++) {
                    acc1[mi][ni] = __builtin_amdgcn_mfma_f32_16x16x32_bf16(af[mi], b1f[ni], acc1[mi][ni], 0, 0, 0);
                    acc3[mi][ni] = __builtin_amdgcn_mfma_f32_16x16x32_bf16(af[mi], b3f[ni], acc3[mi][ni], 0, 0, 0);
                }
        }
    };

    const int NI = DM / BK;   // 8
    #pragma unroll
    for (int i = 0; i < NI; i++) {
        if (i) __syncthreads();
        stage(i * BK);
        __syncthreads();
        compute();
    }
    #pragma unroll
    for (int mi = 0; mi < 2; mi++) {
        #pragma unroll
        for (int r = 0; r < 4; r++) {
            int mloc = wave * 32 + mi * 16 + quad * 4 + r;
            int gi = mt * BM + mloc;
            if (gi < cnt) {
                size_t rowbase = (size_t)(off + gi) * HID + nt * BN;
                #pragma unroll
                for (int ni = 0; ni < 4; ni++) {
                    float z1 = acc1[mi][ni][r];
                    float z3 = acc3[mi][ni][r];
                    float h = (z1 / (1.f + __expf(-z1))) * z3;
                    Hb[rowbase + ni * 16 + l15] = f2bf(h);
                }
            }
        }
    }
}

// ---------------- GEMM2 tile body (128x128, bf16 gated P out) ----------------
__device__ __forceinline__ void gemm2_tile(
    int lid, Smem& sm,
    const unsigned short* __restrict__ Hb, const unsigned short* __restrict__ w2t,
    unsigned short* __restrict__ P, const float* __restrict__ gates,
    const int* __restrict__ counts, const int* __restrict__ offsets) {
    const int xcd = lid & 7;
    const int j = lid >> 3;
    const int gy = xcd * (MAXTILE / 8) + (j >> 2);
    const int nt = j & 3;
    int e, mt, cnt, off;
    if (!tile_lookup(counts, offsets, gy, e, mt, cnt, off)) return;

    unsigned short* As = sm.g2.As;
    unsigned short* Bs = sm.g2.Bs;

    const int tid = threadIdx.x;
    const int lane = tid & 63, wave = tid >> 6;
    const int lrow8 = lane >> 3;
    const int lchunk = (lane & 7) ^ lrow8;

    const unsigned short* a_g[4];
    #pragma unroll
    for (int i = 0; i < 4; i++) {
        int r = (wave * 4 + i) * 8 + lrow8;
        int sl = off + mt * BM + r;
        if (sl >= NSLOT) sl = NSLOT - 1;
        a_g[i] = Hb + (size_t)sl * HID + lchunk * 8;
    }
    const unsigned short* b_g[4];
    #pragma unroll
    for (int i = 0; i < 4; i++) {
        int r = (wave * 4 + i) * 8 + lrow8;
        b_g[i] = w2t + ((size_t)e * DM + nt * BN2 + r) * HID + lchunk * 8;
    }

    const int l15 = lane & 15, quad = lane >> 4;
    const int sw = l15 & 7;

    floatx4 acc[2][8];
    #pragma unroll
    for (int i = 0; i < 2; i++)
        #pragma unroll
        for (int j2 = 0; j2 < 8; j2++) acc[i][j2] = (floatx4){0.f, 0.f, 0.f, 0.f};

    __syncthreads();   // LDS free from previous tile/phase

    auto stage = [&](int k0) {
        #pragma unroll
        for (int i = 0; i < 4; i++) load16_lds(a_g[i] + k0, &As[(wave * 4 + i) * 512]);
        #pragma unroll
        for (int i = 0; i < 4; i++) load16_lds(b_g[i] + k0, &Bs[(wave * 4 + i) * 512]);
    };
    auto compute = [&]() {
        #pragma unroll
        for (int kk = 0; kk < 2; kk++) {
            const int qc = kk * 4 + quad;
            const int ch = (qc ^ sw) << 3;
            bf16x8 af[2], bf[8];
            #pragma unroll
            for (int mi = 0; mi < 2; mi++)
                af[mi] = *(const bf16x8*)(&As[(wave * 32 + mi * 16 + l15) * 64 + ch]);
            #pragma unroll
            for (int ni = 0; ni < 8; ni++)
                bf[ni] = *(const bf16x8*)(&Bs[(ni * 16 + l15) * 64 + ch]);
            #pragma unroll
            for (int mi = 0; mi < 2; mi++)
                #pragma unroll
                for (int ni = 0; ni < 8; ni++)
                    acc[mi][ni] = __builtin_amdgcn_mfma_f32_16x16x32_bf16(af[mi], bf[ni], acc[mi][ni], 0, 0, 0);
        }
    };

    const int NI = HID / BK;   // 16
    #pragma unroll
    for (int i = 0; i < NI; i++) {
        if (i) __syncthreads();
        stage(i * BK);
        __syncthreads();
        compute();
    }
    #pragma unroll
    for (int mi = 0; mi < 2; mi++) {
        #pragma unroll
        for (int r = 0; r < 4; r++) {
            int mloc = wave * 32 + mi * 16 + quad * 4 + r;
            int gi = mt * BM + mloc;
            if (gi < cnt) {
                int slot = off + gi;
                float g = gates[slot];
                #pragma unroll
                for (int ni = 0; ni < 8; ni++) {
                    int col = nt * BN2 + ni * 16 + l15;
                    P[(size_t)slot * DM + col] = f2bf(g * acc[mi][ni][r]);
                }
            }
        }
    }
}

// ================= persistent cooperative mega-kernel =================
// All phases in ONE dispatch; grid.sync() between phases removes ~90us of
// serialized node-boundary dead time (R5 analysis: kernel sum ~110us of a
// 200us total). 1024 blocks x 256 thr, 32KB LDS, launch_bounds(256,4) ->
// 4 blocks/CU co-resident (LDS limit is 5).
__global__ __launch_bounds__(256, 4) void moe_mega(
    const float* __restrict__ x, const float* __restrict__ Wg, const float* __restrict__ bg,
    const float* __restrict__ W1, const float* __restrict__ W3, const float* __restrict__ W2,
    unsigned short* __restrict__ w1t, unsigned short* __restrict__ w3t,
    unsigned short* __restrict__ w2t, unsigned short* __restrict__ xb,
    unsigned short* __restrict__ Hb,
    int* __restrict__ top_idx, float* __restrict__ top_p, int* __restrict__ block_hist,
    int* __restrict__ counts, int* __restrict__ offsets,
    int* __restrict__ rows, float* __restrict__ gates, int* __restrict__ slot_of,
    unsigned short* __restrict__ P, float* __restrict__ y) {
    cg::grid_group grid = cg::this_grid();
    __shared__ Smem sm;
    const int tid = threadIdx.x;
    const int bid = blockIdx.x;

    // ---- Phase A: cvt (units 0..3071) + router (units 3072..5119); 5 units/block ----
    for (int u = bid; u < 5120; u += GRID) {
        if (u < 3072) {
            const int wsel = u >> 10;
            const float* src; unsigned short* dst; int K, N;
            if (wsel == 0)      { src = W1; dst = w1t; K = DM;  N = HID; }
            else if (wsel == 1) { src = W3; dst = w3t; K = DM;  N = HID; }
            else                { src = W2; dst = w2t; K = HID; N = DM;  }
            const int tkn = (K >> 6) * (N >> 6);     // 128
            int b = u & 1023;
            int e = b / tkn;
            int rem = b % tkn;
            const int tn6 = N >> 6;
            int kt = rem / tn6, nt = rem % tn6;
            int tx = tid & 15, ty = tid >> 4;
            const float* s = src + ((size_t)(e * K + kt * 64 + ty)) * N + nt * 64 + tx * 4;
            #pragma unroll
            for (int i = 0; i < 4; i++) {
                float4 v = *(const float4*)(s + (size_t)(i * 16) * N);
                float* tr = &sm.cvt[ty + i * 16][tx * 4];
                tr[0] = v.x; tr[1] = v.y; tr[2] = v.z; tr[3] = v.w;
            }
            __syncthreads();
            int n = tid >> 3;
            int c8 = (tid & 7) * 8;
            unsigned short* d = dst + ((size_t)(e * N + nt * 64)) * K + kt * 64;
            #pragma unroll
            for (int i = 0; i < 2; i++) {
                int nn = n + i * 32;
                u16x8 r;
                #pragma unroll
                for (int kk = 0; kk < 8; kk++) r[kk] = f2bf(sm.cvt[c8 + kk][nn]);
                *(u16x8*)(d + (size_t)nn * K + c8) = r;
            }
        } else {
            int lane = tid & 63, wave = tid >> 6;
            int t = (u - 3072) * 4 + wave;
            float acc[NE];
            #pragma unroll
            for (int e = 0; e < NE; e++) acc[e] = 0.f;
            const float* xr = x + (size_t)t * DM;
            unsigned short* xbr = xb + (size_t)t * DM;
            #pragma unroll
            for (int j = 0; j < 8; j++) {
                int d = lane + j * 64;
                float xv = xr[d];
                xbr[d] = f2bf(xv);
                const float4* wr = (const float4*)(Wg + (size_t)d * NE);
                float4 w0 = wr[0], w1 = wr[1];
                acc[0] += xv * w0.x; acc[1] += xv * w0.y; acc[2] += xv * w0.z; acc[3] += xv * w0.w;
                acc[4] += xv * w1.x; acc[5] += xv * w1.y; acc[6] += xv * w1.z; acc[7] += xv * w1.w;
            }
            #pragma unroll
            for (int e = 0; e < NE; e++) {
                float v = acc[e];
                #pragma unroll
                for (int off = 32; off > 0; off >>= 1) v += __shfl_down(v, off, 64);
                acc[e] = v;
            }
            if (lane == 0) {
                float best = -1e30f, second = -1e30f;
                int bi = 0, si = 0;
                #pragma unroll
                for (int e = 0; e < NE; e++) {
                    float v = acc[e] + bg[e];
                    if (v > best) { second = best; si = bi; best = v; bi = e; }
                    else if (v > second) { second = v; si = e; }
                }
                float ex = __expf(second - best);
                float inv = 1.f / (1.f + ex);
                top_idx[t * 2] = bi;  top_idx[t * 2 + 1] = si;
                top_p[t * 2] = inv;   top_p[t * 2 + 1] = ex * inv;
            }
        }
        __syncthreads();
    }
    __threadfence(); grid.sync();

    // ---- Phase B: per-chunk histogram (blocks 0..31) ----
    if (bid < NB) {
        if (tid < NE) sm.s.h[tid] = 0;
        __syncthreads();
        int t = bid * 256 + tid;
        atomicAdd(&sm.s.h[top_idx[t * 2]], 1);
        atomicAdd(&sm.s.h[top_idx[t * 2 + 1]], 1);
        __syncthreads();
        if (tid < NE) block_hist[bid * NE + tid] = sm.s.h[tid];
    }
    __threadfence(); grid.sync();

    // ---- Phase C: build (each block recomputes prefix locally; block 0 publishes) ----
    if (bid < NB) {
        if (tid < NE) {
            int run = 0, mybase = 0;
            for (int bb = 0; bb < NB; bb++) {
                if (bb == bid) mybase = run;
                run += block_hist[bb * NE + tid];
            }
            sm.s.cnt[tid] = run;
            sm.s.h[tid] = mybase;
        }
        __syncthreads();
        if (tid < NE) {
            int offs = 0;
            for (int ee = 0; ee < tid; ee++) offs += sm.s.cnt[ee];
            sm.s.cur[tid] = offs + sm.s.h[tid];
            if (bid == 0) { counts[tid] = sm.s.cnt[tid]; offsets[tid] = offs; }
        }
        __syncthreads();
        int t = bid * 256 + tid;
        #pragma unroll
        for (int k = 0; k < 2; k++) {
            int e = top_idx[t * 2 + k];
            int slot = atomicAdd(&sm.s.cur[e], 1);
            rows[slot] = t;
            gates[slot] = top_p[t * 2 + k];
            slot_of[t * 2 + k] = slot;
        }
    }
    __threadfence(); grid.sync();

    // ---- Phase D: gemm1 (2176 tiles, grid-stride) ----
    for (int lid = bid; lid < 16 * MAXTILE; lid += GRID)
        gemm1_tile(lid, sm, xb, w1t, w3t, Hb, rows, counts, offsets);
    __threadfence(); grid.sync();

    // ---- Phase E: gemm2 (544 tiles) ----
    for (int lid = bid; lid < 4 * MAXTILE; lid += GRID)
        gemm2_tile(lid, sm, Hb, w2t, P, gates, counts, offsets);
    __threadfence(); grid.sync();

    // ---- Phase F: combine (exactly 2 groups of 8 elems per thread) ----
    for (int g = bid * 256 + tid; g < TOKENS * (DM / 8); g += GRID * 256) {
        int t = g / (DM / 8);
        int c8 = g % (DM / 8);
        int s0 = slot_of[t * 2], s1 = slot_of[t * 2 + 1];
        uint4 a = *(const uint4*)(P + (size_t)s0 * DM + c8 * 8);
        uint4 b = *(const uint4*)(P + (size_t)s1 * DM + c8 * 8);
        float o[8];
        const unsigned* aw = (const unsigned*)&a;
        const unsigned* bw = (const unsigned*)&b;
        #pragma unroll
        for (int j = 0; j < 4; j++) {
            union { unsigned u; float f; } al, ah, bl, bh;
            al.u = aw[j] << 16; ah.u = aw[j] & 0xffff0000u;
            bl.u = bw[j] << 16; bh.u = bw[j] & 0xffff0000u;
            o[j * 2]     = al.f + bl.f;
            o[j * 2 + 1] = ah.f + bh.f;
        }
        float4* yo = (float4*)(y + (size_t)t * DM + c8 * 8);
        yo[0] = make_float4(o[0], o[1], o[2], o[3]);
        yo[1] = make_float4(o[4], o[5], o[6], o[7]);
    }
}

// ================= fallback multi-kernel path (proven R5, ~200us) =================

__global__ void prep_kernel(const float* __restrict__ x, const float* __restrict__ Wg,
                            const float* __restrict__ bg,
                            const float* __restrict__ W1, const float* __restrict__ W3,
                            const float* __restrict__ W2,
                            unsigned short* __restrict__ w1t, unsigned short* __restrict__ w3t,
                            unsigned short* __restrict__ w2t,
                            int* __restrict__ top_idx, float* __restrict__ top_p,
                            unsigned short* __restrict__ xb) {
    if (blockIdx.x < 3072) {
        __shared__ float tile[64][65];
        const int cb = blockIdx.x;
        const int wsel = cb >> 10;
        const float* src; unsigned short* dst; int K, N;
        if (wsel == 0)      { src = W1; dst = w1t; K = DM;  N = HID; }
        else if (wsel == 1) { src = W3; dst = w3t; K = DM;  N = HID; }
        else                { src = W2; dst = w2t; K = HID; N = DM;  }
        const int tkn = (K >> 6) * (N >> 6);
        int b = cb & 1023;
        int e = b / tkn;
        int rem = b % tkn;
        const int tn6 = N >> 6;
        int kt = rem / tn6, nt = rem % tn6;
        int tx = threadIdx.x & 15, ty = threadIdx.x >> 4;
        const float* s = src + ((size_t)(e * K + kt * 64 + ty)) * N + nt * 64 + tx * 4;
        #pragma unroll
        for (int i = 0; i < 4; i++) {
            float4 v = *(const float4*)(s + (size_t)(i * 16) * N);
            float* tr = &tile[ty + i * 16][tx * 4];
            tr[0] = v.x; tr[1] = v.y; tr[2] = v.z; tr[3] = v.w;
        }
        __syncthreads();
        int n = threadIdx.x >> 3;
        int c8 = (threadIdx.x & 7) * 8;
        unsigned short* d = dst + ((size_t)(e * N + nt * 64)) * K + kt * 64;
        #pragma unroll
        for (int i = 0; i < 2; i++) {
            int nn = n + i * 32;
            u16x8 r;
            #pragma unroll
            for (int kk = 0; kk < 8; kk++) r[kk] = f2bf(tile[c8 + kk][nn]);
            *(u16x8*)(d + (size_t)nn * K + c8) = r;
        }
    } else {
        int lane = threadIdx.x & 63, wave = threadIdx.x >> 6;
        int t = (blockIdx.x - 3072) * 4 + wave;
        float acc[NE];
        #pragma unroll
        for (int e = 0; e < NE; e++) acc[e] = 0.f;
        const float* xr = x + (size_t)t * DM;
        unsigned short* xbr = xb + (size_t)t * DM;
        #pragma unroll
        for (int j = 0; j < 8; j++) {
            int d = lane + j * 64;
            float xv = xr[d];
            xbr[d] = f2bf(xv);
            const float4* wr = (const float4*)(Wg + (size_t)d * NE);
            float4 w0 = wr[0], w1 = wr[1];
            acc[0] += xv * w0.x; acc[1] += xv * w0.y; acc[2] += xv * w0.z; acc[3] += xv * w0.w;
            acc[4] += xv * w1.x; acc[5] += xv * w1.y; acc[6] += xv * w1.z; acc[7] += xv * w1.w;
        }
        #pragma unroll
        for (int e = 0; e < NE; e++) {
            float v = acc[e];
            #pragma unroll
            for (int off = 32; off > 0; off >>= 1) v += __shfl_down(v, off, 64);
            acc[e] = v;
        }
        if (lane == 0) {
            float best = -1e30f, second = -1e30f;
            int bi = 0, si = 0;
            #pragma unroll
            for (int e = 0; e < NE; e++) {
                float v = acc[e] + bg[e];
                if (v > best) { second = best; si = bi; best = v; bi = e; }
                else if (v > second) { second = v; si = e; }
            }
            float ex = __expf(second - best);
            float inv = 1.f / (1.f + ex);
            top_idx[t * 2] = bi;  top_idx[t * 2 + 1] = si;
            top_p[t * 2] = inv;   top_p[t * 2 + 1] = ex * inv;
        }
    }
}

__global__ void hist_kernel(const int* __restrict__ top_idx, int* __restrict__ block_hist) {
    __shared__ int h[NE];
    int b = blockIdx.x, tid = threadIdx.x;
    if (tid < NE) h[tid] = 0;
    __syncthreads();
    int t = b * 256 + tid;
    atomicAdd(&h[top_idx[t * 2]], 1);
    atomicAdd(&h[top_idx[t * 2 + 1]], 1);
    __syncthreads();
    if (tid < NE) block_hist[b * NE + tid] = h[tid];
}

__global__ void prefix_kernel(const int* __restrict__ block_hist, int* __restrict__ counts,
                              int* __restrict__ offsets, int* __restrict__ bases) {
    int e = threadIdx.x;
    if (e < NE) {
        int run = 0;
        for (int b = 0; b < NB; b++) { bases[b * NE + e] = run; run += block_hist[b * NE + e]; }
        counts[e] = run;
    }
    __syncthreads();
    if (e == 0) {
        int s = 0;
        for (int ee = 0; ee < NE; ee++) { offsets[ee] = s; s += counts[ee]; }
    }
    __syncthreads();
    if (e < NE) {
        int off = offsets[e];
        for (int b = 0; b < NB; b++) bases[b * NE + e] += off;
    }
}

__global__ void build_kernel(const int* __restrict__ top_idx, const float* __restrict__ top_p,
                             const int* __restrict__ bases,
                             int* __restrict__ rows, float* __restrict__ gates,
                             int* __restrict__ slot_of) {
    __shared__ int cur[NE];
    int b = blockIdx.x, tid = threadIdx.x;
    if (tid < NE) cur[tid] = bases[b * NE + tid];
    __syncthreads();
    int t = b * 256 + tid;
    #pragma unroll
    for (int k = 0; k < 2; k++) {
        int e = top_idx[t * 2 + k];
        int slot = atomicAdd(&cur[e], 1);
        rows[slot] = t;
        gates[slot] = top_p[t * 2 + k];
        slot_of[t * 2 + k] = slot;
    }
}

__global__ __launch_bounds__(256) void gemm1_kernel(
    const unsigned short* __restrict__ xb, const unsigned short* __restrict__ w1t,
    const unsigned short* __restrict__ w3t, unsigned short* __restrict__ Hb,
    const int* __restrict__ rows, const int* __restrict__ counts,
    const int* __restrict__ offsets) {
    __shared__ Smem sm;
    gemm1_tile(blockIdx.x, sm, xb, w1t, w3t, Hb, rows, counts, offsets);
}

__global__ __launch_bounds__(256) void gemm2_kernel(
    const unsigned short* __restrict__ Hb, const unsigned short* __restrict__ w2t,
    unsigned short* __restrict__ P, const float* __restrict__ gates,
    const int* __restrict__ counts, const int* __restrict__ offsets) {
    __shared__ Smem sm;
    gemm2_tile(blockIdx.x, sm, Hb, w2t, P, gates, counts, offsets);
}

__global__ void combine_kernel(const unsigned short* __restrict__ P,
                               const int* __restrict__ slot_of, float* __restrict__ y) {
    int i = blockIdx.x * blockDim.x + threadIdx.x;
    int t = i / (DM / 8);
    int c8 = i % (DM / 8);
    int s0 = slot_of[t * 2], s1 = slot_of[t * 2 + 1];
    uint4 a = *(const uint4*)(P + (size_t)s0 * DM + c8 * 8);
    uint4 b = *(const uint4*)(P + (size_t)s1 * DM + c8 * 8);
    float o[8];
    const unsigned* aw = (const unsigned*)&a;
    const unsigned* bw = (const unsigned*)&b;
    #pragma unroll
    for (int j = 0; j < 4; j++) {
        union { unsigned u; float f; } al, ah, bl, bh;
        al.u = aw[j] << 16; ah.u = aw[j] & 0xffff0000u;
        bl.u = bw[j] << 16; bh.u = bw[j] & 0xffff0000u;
        o[j * 2]     = al.f + bl.f;
        o[j * 2 + 1] = ah.f + bh.f;
    }
    float4* yo = (float4*)(y + (size_t)t * DM + c8 * 8);
    yo[0] = make_float4(o[0], o[1], o[2], o[3]);
    yo[1] = make_float4(o[4], o[5], o[6], o[7]);
}

extern "C" void kernel_launch(void* const* d_in, const int* in_sizes, int n_in,
                              void* d_out, int out_size, void* d_ws, size_t ws_size,
                              hipStream_t stream) {
    (void)in_sizes; (void)n_in; (void)out_size; (void)ws_size;
    const float* x  = (const float*)d_in[0];
    const float* Wg = (const float*)d_in[1];
    const float* bg = (const float*)d_in[2];
    const float* W1 = (const float*)d_in[3];
    const float* W3 = (const float*)d_in[4];
    const float* W2 = (const float*)d_in[5];
    float* y = (float*)d_out;

    char* p = (char*)d_ws;
    auto carve = [&](size_t bytes) -> char* {
        char* r = p;
        p += (bytes + 255) & ~(size_t)255;
        return r;
    };
    unsigned short* w1t  = (unsigned short*)carve((size_t)NE * DM * HID * 2);   // 8 MB
    unsigned short* w3t  = (unsigned short*)carve((size_t)NE * DM * HID * 2);   // 8 MB (contiguous)
    unsigned short* w2t  = (unsigned short*)carve((size_t)NE * HID * DM * 2);
    unsigned short* xb   = (unsigned short*)carve((size_t)TOKENS * DM * 2);
    unsigned short* Hb   = (unsigned short*)carve((size_t)NSLOT * HID * 2);
    int*   rows    = (int*)carve(NSLOT * 4);
    float* gates   = (float*)carve(NSLOT * 4);
    int*   slot_of = (int*)carve(NSLOT * 4);
    int*   tidx    = (int*)carve((size_t)TOKENS * 2 * 4);
    float* tp      = (float*)carve((size_t)TOKENS * 2 * 4);
    int*   counts  = (int*)carve(256);
    int*   offsets = (int*)carve(256);
    int*   bhist   = (int*)carve((size_t)NB * NE * 4);
    int*   bases   = (int*)carve((size_t)NB * NE * 4);
    // P (bf16, 16 MB) aliases w1t+w3t (16 MB) — dead after gemm1 completes.
    unsigned short* P = w1t;

    // ---- preferred: single cooperative persistent kernel ----
    {
        const float* xa = x; const float* Wga = Wg; const float* bga = bg;
        const float* W1a = W1; const float* W3a = W3; const float* W2a = W2;
        unsigned short* w1ta = w1t; unsigned short* w3ta = w3t; unsigned short* w2ta = w2t;
        unsigned short* xba = xb; unsigned short* Hba = Hb;
        int* tidxa = tidx; float* tpa = tp; int* bhista = bhist;
        int* countsa = counts; int* offsetsa = offsets;
        int* rowsa = rows; float* gatesa = gates; int* slot_ofa = slot_of;
        unsigned short* Pa = P; float* ya = y;
        void* args[] = {
            &xa, &Wga, &bga, &W1a, &W3a, &W2a,
            &w1ta, &w3ta, &w2ta, &xba, &Hba,
            &tidxa, &tpa, &bhista, &countsa, &offsetsa,
            &rowsa, &gatesa, &slot_ofa, &Pa, &ya
        };
        hipError_t err = hipLaunchCooperativeKernel(
            (const void*)moe_mega, dim3(GRID), dim3(256), args, 0, stream);
        if (err == hipSuccess) return;
        (void)hipGetLastError();   // clear sticky error, fall through to multi-kernel path
    }

    // ---- fallback: proven R5 multi-kernel path ----
    prep_kernel<<<dim3(3072 + TOKENS / 4), dim3(256), 0, stream>>>(
        x, Wg, bg, W1, W3, W2, w1t, w3t, w2t, tidx, tp, xb);
    hist_kernel<<<dim3(NB), dim3(256), 0, stream>>>(tidx, bhist);
    prefix_kernel<<<dim3(1), dim3(64), 0, stream>>>(bhist, counts, offsets, bases);
    build_kernel<<<dim3(NB), dim3(256), 0, stream>>>(tidx, tp, bases, rows, gates, slot_of);
    gemm1_kernel<<<dim3((HID / BN) * MAXTILE), dim3(256), 0, stream>>>(xb, w1t, w3t, Hb, rows, counts, offsets);
    gemm2_kernel<<<dim3((DM / BN2) * MAXTILE), dim3(256), 0, stream>>>(Hb, w2t, P, gates, counts, offsets);
    combine_kernel<<<dim3((TOKENS * DM / 8) / 256), dim3(256), 0, stream>>>(P, slot_of, y);
}

// Round 7
// 715.935 us; speedup vs baseline: 1.7391x; 1.7391x over previous
//
#include <hip/hip_runtime.h>
#include <hip/hip_bf16.h>
#include <hip/hip_cooperative_groups.h>

namespace cg = cooperative_groups;

#define TOKENS 8192
#define DM 512
#define NE 8
#define HID 1024
#define NSLOT (TOKENS * 2)
#define NB 32          // token blocks for hist/build (256 tokens each)

#define BM 128
#define BN 64
#define BK 64
#define BN2 128        // gemm2 N-tile
#define MAXTILE 136    // 8 * 17, > sum ceil(counts[e]/BM) worst case (135)

// persistent blocks: 2 blocks/CU x 256 CU. launch_bounds(256,2) -> 256-reg cap
// (R6 post-mortem: (256,4) capped regs at 128 total incl AGPRs -> accumulators
// forced ~80 regs of addressing into scratch: VGPR_Count 64, +75MB spill
// writes, MfmaUtil 1.8%, 6x slowdown. 2 waves/EU leaves the ~160 the GEMM
// phases need.)
#define GRID 512

typedef __bf16 bf16x8 __attribute__((ext_vector_type(8)));
typedef float floatx4 __attribute__((ext_vector_type(4)));
typedef unsigned short u16x8 __attribute__((ext_vector_type(8)));

__device__ __forceinline__ unsigned short f2bf(float f) {
    union { float f; unsigned u; } c; c.f = f;
    unsigned u = c.u;
    u += 0x7fffu + ((u >> 16) & 1u);   // RNE
    return (unsigned short)(u >> 16);
}

// async global->LDS, 16B per lane, LDS dest = wave-uniform base + lane*16
__device__ __forceinline__ void load16_lds(const void* g, void* l) {
    __builtin_amdgcn_global_load_lds(
        (const __attribute__((address_space(1))) unsigned int*)g,
        (__attribute__((address_space(3))) unsigned int*)l, 16, 0, 0);
}

// 32 KB shared-memory union — one allocation reused by every phase
union Smem {
    float cvt[64][65];                                                        // prep/cvt (16.6 KB)
    struct { unsigned short As[BM * BK], B1s[BN * BK], B3s[BN * BK]; } g1;    // gemm1 (32 KB)
    struct { unsigned short As[BM * BK], Bs[BN2 * BK]; } g2;                  // gemm2 (32 KB)
    struct { int h[NE]; int cnt[NE]; int cur[NE]; } s;                        // hist/build
};

// map compact tile id gy -> (expert e, tile mt); returns false past the end
__device__ __forceinline__ bool tile_lookup(const int* counts, const int* offsets, int gy,
                                            int& e, int& mt, int& cnt, int& off) {
    int bacc = 0;
    #pragma unroll
    for (int ee = 0; ee < NE; ee++) {
        int c = counts[ee];
        int ntl = (c + BM - 1) >> 7;
        if (gy < bacc + ntl) { e = ee; mt = gy - bacc; cnt = c; off = offsets[ee]; return true; }
        bacc += ntl;
    }
    return false;
}

// ---------------- GEMM1 tile body (proven ~723 TF structure) ----------------
__device__ __forceinline__ void gemm1_tile(
    int lid, Smem& sm,
    const unsigned short* __restrict__ xb, const unsigned short* __restrict__ w1t,
    const unsigned short* __restrict__ w3t, unsigned short* __restrict__ Hb,
    const int* __restrict__ rows, const int* __restrict__ counts,
    const int* __restrict__ offsets) {
    const int xcd = lid & 7;
    const int j = lid >> 3;
    const int gy = xcd * (MAXTILE / 8) + (j >> 4);
    const int nt = j & 15;
    int e, mt, cnt, off;
    if (!tile_lookup(counts, offsets, gy, e, mt, cnt, off)) return;

    unsigned short* As  = sm.g1.As;
    unsigned short* B1s = sm.g1.B1s;
    unsigned short* B3s = sm.g1.B3s;

    const int tid = threadIdx.x;
    const int lane = tid & 63, wave = tid >> 6;
    const int lrow8 = lane >> 3;
    const int lchunk = (lane & 7) ^ lrow8;

    const unsigned short* a_g[4];
    #pragma unroll
    for (int i = 0; i < 4; i++) {
        int r = (wave * 4 + i) * 8 + lrow8;
        int gr = mt * BM + r;
        int tok = rows[off + (gr < cnt ? gr : 0)];
        a_g[i] = xb + (size_t)tok * DM + lchunk * 8;
    }
    const unsigned short* b1_g[2]; const unsigned short* b3_g[2];
    #pragma unroll
    for (int i = 0; i < 2; i++) {
        int r = (wave * 2 + i) * 8 + lrow8;
        b1_g[i] = w1t + ((size_t)e * HID + nt * BN + r) * DM + lchunk * 8;
        b3_g[i] = w3t + ((size_t)e * HID + nt * BN + r) * DM + lchunk * 8;
    }

    const int l15 = lane & 15, quad = lane >> 4;
    const int sw = l15 & 7;

    floatx4 acc1[2][4], acc3[2][4];
    #pragma unroll
    for (int i = 0; i < 2; i++)
        #pragma unroll
        for (int j2 = 0; j2 < 4; j2++) {
            acc1[i][j2] = (floatx4){0.f, 0.f, 0.f, 0.f};
            acc3[i][j2] = (floatx4){0.f, 0.f, 0.f, 0.f};
        }

    __syncthreads();   // LDS free from previous tile/phase

    auto stage = [&](int k0) {
        #pragma unroll
        for (int i = 0; i < 4; i++) load16_lds(a_g[i] + k0, &As[(wave * 4 + i) * 512]);
        #pragma unroll
        for (int i = 0; i < 2; i++) {
            load16_lds(b1_g[i] + k0, &B1s[(wave * 2 + i) * 512]);
            load16_lds(b3_g[i] + k0, &B3s[(wave * 2 + i) * 512]);
        }
    };
    auto compute = [&]() {
        #pragma unroll
        for (int kk = 0; kk < 2; kk++) {
            const int qc = kk * 4 + quad;
            const int ch = (qc ^ sw) << 3;
            bf16x8 af[2], b1f[4], b3f[4];
            #pragma unroll
            for (int mi = 0; mi < 2; mi++)
                af[mi] = *(const bf16x8*)(&As[(wave * 32 + mi * 16 + l15) * 64 + ch]);
            #pragma unroll
            for (int ni = 0; ni < 4; ni++) {
                b1f[ni] = *(const bf16x8*)(&B1s[(ni * 16 + l15) * 64 + ch]);
                b3f[ni] = *(const bf16x8*)(&B3s[(ni * 16 + l15) * 64 + ch]);
            }
            #pragma unroll
            for (int mi = 0; mi < 2; mi++)
                #pragma unroll
                for (int ni = 0; ni < 4; ni++) {
                    acc1[mi][ni] = __builtin_amdgcn_mfma_f32_16x16x32_bf16(af[mi], b1f[ni], acc1[mi][ni], 0, 0, 0);
                    acc3[mi][ni] = __builtin_amdgcn_mfma_f32_16x16x32_bf16(af[mi], b3f[ni], acc3[mi][ni], 0, 0, 0);
                }
        }
    };

    const int NI = DM / BK;   // 8
    #pragma unroll
    for (int i = 0; i < NI; i++) {
        if (i) __syncthreads();
        stage(i * BK);
        __syncthreads();
        compute();
    }
    #pragma unroll
    for (int mi = 0; mi < 2; mi++) {
        #pragma unroll
        for (int r = 0; r < 4; r++) {
            int mloc = wave * 32 + mi * 16 + quad * 4 + r;
            int gi = mt * BM + mloc;
            if (gi < cnt) {
                size_t rowbase = (size_t)(off + gi) * HID + nt * BN;
                #pragma unroll
                for (int ni = 0; ni < 4; ni++) {
                    float z1 = acc1[mi][ni][r];
                    float z3 = acc3[mi][ni][r];
                    float h = (z1 / (1.f + __expf(-z1))) * z3;
                    Hb[rowbase + ni * 16 + l15] = f2bf(h);
                }
            }
        }
    }
}

// ---------------- GEMM2 tile body (128x128, bf16 gated P out) ----------------
__device__ __forceinline__ void gemm2_tile(
    int lid, Smem& sm,
    const unsigned short* __restrict__ Hb, const unsigned short* __restrict__ w2t,
    unsigned short* __restrict__ P, const float* __restrict__ gates,
    const int* __restrict__ counts, const int* __restrict__ offsets) {
    const int xcd = lid & 7;
    const int j = lid >> 3;
    const int gy = xcd * (MAXTILE / 8) + (j >> 2);
    const int nt = j & 3;
    int e, mt, cnt, off;
    if (!tile_lookup(counts, offsets, gy, e, mt, cnt, off)) return;

    unsigned short* As = sm.g2.As;
    unsigned short* Bs = sm.g2.Bs;

    const int tid = threadIdx.x;
    const int lane = tid & 63, wave = tid >> 6;
    const int lrow8 = lane >> 3;
    const int lchunk = (lane & 7) ^ lrow8;

    const unsigned short* a_g[4];
    #pragma unroll
    for (int i = 0; i < 4; i++) {
        int r = (wave * 4 + i) * 8 + lrow8;
        int sl = off + mt * BM + r;
        if (sl >= NSLOT) sl = NSLOT - 1;
        a_g[i] = Hb + (size_t)sl * HID + lchunk * 8;
    }
    const unsigned short* b_g[4];
    #pragma unroll
    for (int i = 0; i < 4; i++) {
        int r = (wave * 4 + i) * 8 + lrow8;
        b_g[i] = w2t + ((size_t)e * DM + nt * BN2 + r) * HID + lchunk * 8;
    }

    const int l15 = lane & 15, quad = lane >> 4;
    const int sw = l15 & 7;

    floatx4 acc[2][8];
    #pragma unroll
    for (int i = 0; i < 2; i++)
        #pragma unroll
        for (int j2 = 0; j2 < 8; j2++) acc[i][j2] = (floatx4){0.f, 0.f, 0.f, 0.f};

    __syncthreads();   // LDS free from previous tile/phase

    auto stage = [&](int k0) {
        #pragma unroll
        for (int i = 0; i < 4; i++) load16_lds(a_g[i] + k0, &As[(wave * 4 + i) * 512]);
        #pragma unroll
        for (int i = 0; i < 4; i++) load16_lds(b_g[i] + k0, &Bs[(wave * 4 + i) * 512]);
    };
    auto compute = [&]() {
        #pragma unroll
        for (int kk = 0; kk < 2; kk++) {
            const int qc = kk * 4 + quad;
            const int ch = (qc ^ sw) << 3;
            bf16x8 af[2], bf[8];
            #pragma unroll
            for (int mi = 0; mi < 2; mi++)
                af[mi] = *(const bf16x8*)(&As[(wave * 32 + mi * 16 + l15) * 64 + ch]);
            #pragma unroll
            for (int ni = 0; ni < 8; ni++)
                bf[ni] = *(const bf16x8*)(&Bs[(ni * 16 + l15) * 64 + ch]);
            #pragma unroll
            for (int mi = 0; mi < 2; mi++)
                #pragma unroll
                for (int ni = 0; ni < 8; ni++)
                    acc[mi][ni] = __builtin_amdgcn_mfma_f32_16x16x32_bf16(af[mi], bf[ni], acc[mi][ni], 0, 0, 0);
        }
    };

    const int NI = HID / BK;   // 16
    #pragma unroll
    for (int i = 0; i < NI; i++) {
        if (i) __syncthreads();
        stage(i * BK);
        __syncthreads();
        compute();
    }
    #pragma unroll
    for (int mi = 0; mi < 2; mi++) {
        #pragma unroll
        for (int r = 0; r < 4; r++) {
            int mloc = wave * 32 + mi * 16 + quad * 4 + r;
            int gi = mt * BM + mloc;
            if (gi < cnt) {
                int slot = off + gi;
                float g = gates[slot];
                #pragma unroll
                for (int ni = 0; ni < 8; ni++) {
                    int col = nt * BN2 + ni * 16 + l15;
                    P[(size_t)slot * DM + col] = f2bf(g * acc[mi][ni][r]);
                }
            }
        }
    }
}

// ================= persistent cooperative mega-kernel (v2) =================
// All phases in ONE dispatch; grid.sync() between phases removes serialized
// node-boundary dead time. 512 blocks x 256 thr (2/CU co-resident), 32KB LDS,
// launch_bounds(256,2) -> 256-reg cap so the GEMM phases (~160 regs incl
// AGPR) do NOT spill (the R6 failure mode).
__global__ __launch_bounds__(256, 2) void moe_mega(
    const float* __restrict__ x, const float* __restrict__ Wg, const float* __restrict__ bg,
    const float* __restrict__ W1, const float* __restrict__ W3, const float* __restrict__ W2,
    unsigned short* __restrict__ w1t, unsigned short* __restrict__ w3t,
    unsigned short* __restrict__ w2t, unsigned short* __restrict__ xb,
    unsigned short* __restrict__ Hb,
    int* __restrict__ top_idx, float* __restrict__ top_p, int* __restrict__ block_hist,
    int* __restrict__ counts, int* __restrict__ offsets,
    int* __restrict__ rows, float* __restrict__ gates, int* __restrict__ slot_of,
    unsigned short* __restrict__ P, float* __restrict__ y) {
    cg::grid_group grid = cg::this_grid();
    __shared__ Smem sm;
    const int tid = threadIdx.x;
    const int bid = blockIdx.x;

    // ---- Phase A: cvt (units 0..3071) + router (units 3072..5119) ----
    for (int u = bid; u < 5120; u += GRID) {
        if (u < 3072) {
            const int wsel = u >> 10;
            const float* src; unsigned short* dst; int K, N;
            if (wsel == 0)      { src = W1; dst = w1t; K = DM;  N = HID; }
            else if (wsel == 1) { src = W3; dst = w3t; K = DM;  N = HID; }
            else                { src = W2; dst = w2t; K = HID; N = DM;  }
            const int tkn = (K >> 6) * (N >> 6);     // 128
            int b = u & 1023;
            int e = b / tkn;
            int rem = b % tkn;
            const int tn6 = N >> 6;
            int kt = rem / tn6, nt = rem % tn6;
            int tx = tid & 15, ty = tid >> 4;
            const float* s = src + ((size_t)(e * K + kt * 64 + ty)) * N + nt * 64 + tx * 4;
            #pragma unroll
            for (int i = 0; i < 4; i++) {
                float4 v = *(const float4*)(s + (size_t)(i * 16) * N);
                float* tr = &sm.cvt[ty + i * 16][tx * 4];
                tr[0] = v.x; tr[1] = v.y; tr[2] = v.z; tr[3] = v.w;
            }
            __syncthreads();
            int n = tid >> 3;
            int c8 = (tid & 7) * 8;
            unsigned short* d = dst + ((size_t)(e * N + nt * 64)) * K + kt * 64;
            #pragma unroll
            for (int i = 0; i < 2; i++) {
                int nn = n + i * 32;
                u16x8 r;
                #pragma unroll
                for (int kk = 0; kk < 8; kk++) r[kk] = f2bf(sm.cvt[c8 + kk][nn]);
                *(u16x8*)(d + (size_t)nn * K + c8) = r;
            }
        } else {
            int lane = tid & 63, wave = tid >> 6;
            int t = (u - 3072) * 4 + wave;
            float acc[NE];
            #pragma unroll
            for (int e = 0; e < NE; e++) acc[e] = 0.f;
            const float* xr = x + (size_t)t * DM;
            unsigned short* xbr = xb + (size_t)t * DM;
            #pragma unroll
            for (int j = 0; j < 8; j++) {
                int d = lane + j * 64;
                float xv = xr[d];
                xbr[d] = f2bf(xv);
                const float4* wr = (const float4*)(Wg + (size_t)d * NE);
                float4 w0 = wr[0], w1 = wr[1];
                acc[0] += xv * w0.x; acc[1] += xv * w0.y; acc[2] += xv * w0.z; acc[3] += xv * w0.w;
                acc[4] += xv * w1.x; acc[5] += xv * w1.y; acc[6] += xv * w1.z; acc[7] += xv * w1.w;
            }
            #pragma unroll
            for (int e = 0; e < NE; e++) {
                float v = acc[e];
                #pragma unroll
                for (int off = 32; off > 0; off >>= 1) v += __shfl_down(v, off, 64);
                acc[e] = v;
            }
            if (lane == 0) {
                float best = -1e30f, second = -1e30f;
                int bi = 0, si = 0;
                #pragma unroll
                for (int e = 0; e < NE; e++) {
                    float v = acc[e] + bg[e];
                    if (v > best) { second = best; si = bi; best = v; bi = e; }
                    else if (v > second) { second = v; si = e; }
                }
                float ex = __expf(second - best);
                float inv = 1.f / (1.f + ex);
                top_idx[t * 2] = bi;  top_idx[t * 2 + 1] = si;
                top_p[t * 2] = inv;   top_p[t * 2 + 1] = ex * inv;
            }
        }
        __syncthreads();
    }
    __threadfence(); grid.sync();

    // ---- Phase B: per-chunk histogram (blocks 0..31) ----
    if (bid < NB) {
        if (tid < NE) sm.s.h[tid] = 0;
        __syncthreads();
        int t = bid * 256 + tid;
        atomicAdd(&sm.s.h[top_idx[t * 2]], 1);
        atomicAdd(&sm.s.h[top_idx[t * 2 + 1]], 1);
        __syncthreads();
        if (tid < NE) block_hist[bid * NE + tid] = sm.s.h[tid];
    }
    __threadfence(); grid.sync();

    // ---- Phase C: build (each block recomputes prefix locally; block 0 publishes) ----
    if (bid < NB) {
        if (tid < NE) {
            int run = 0, mybase = 0;
            for (int bb = 0; bb < NB; bb++) {
                if (bb == bid) mybase = run;
                run += block_hist[bb * NE + tid];
            }
            sm.s.cnt[tid] = run;
            sm.s.h[tid] = mybase;
        }
        __syncthreads();
        if (tid < NE) {
            int offs = 0;
            for (int ee = 0; ee < tid; ee++) offs += sm.s.cnt[ee];
            sm.s.cur[tid] = offs + sm.s.h[tid];
            if (bid == 0) { counts[tid] = sm.s.cnt[tid]; offsets[tid] = offs; }
        }
        __syncthreads();
        int t = bid * 256 + tid;
        #pragma unroll
        for (int k = 0; k < 2; k++) {
            int e = top_idx[t * 2 + k];
            int slot = atomicAdd(&sm.s.cur[e], 1);
            rows[slot] = t;
            gates[slot] = top_p[t * 2 + k];
            slot_of[t * 2 + k] = slot;
        }
    }
    __threadfence(); grid.sync();

    // ---- Phase D: gemm1 (2176 tiles, grid-stride) ----
    for (int lid = bid; lid < 16 * MAXTILE; lid += GRID)
        gemm1_tile(lid, sm, xb, w1t, w3t, Hb, rows, counts, offsets);
    __threadfence(); grid.sync();

    // ---- Phase E: gemm2 (544 tiles) ----
    for (int lid = bid; lid < 4 * MAXTILE; lid += GRID)
        gemm2_tile(lid, sm, Hb, w2t, P, gates, counts, offsets);
    __threadfence(); grid.sync();

    // ---- Phase F: combine ----
    for (int g = bid * 256 + tid; g < TOKENS * (DM / 8); g += GRID * 256) {
        int t = g / (DM / 8);
        int c8 = g % (DM / 8);
        int s0 = slot_of[t * 2], s1 = slot_of[t * 2 + 1];
        uint4 a = *(const uint4*)(P + (size_t)s0 * DM + c8 * 8);
        uint4 b = *(const uint4*)(P + (size_t)s1 * DM + c8 * 8);
        float o[8];
        const unsigned* aw = (const unsigned*)&a;
        const unsigned* bw = (const unsigned*)&b;
        #pragma unroll
        for (int j = 0; j < 4; j++) {
            union { unsigned u; float f; } al, ah, bl, bh;
            al.u = aw[j] << 16; ah.u = aw[j] & 0xffff0000u;
            bl.u = bw[j] << 16; bh.u = bw[j] & 0xffff0000u;
            o[j * 2]     = al.f + bl.f;
            o[j * 2 + 1] = ah.f + bh.f;
        }
        float4* yo = (float4*)(y + (size_t)t * DM + c8 * 8);
        yo[0] = make_float4(o[0], o[1], o[2], o[3]);
        yo[1] = make_float4(o[4], o[5], o[6], o[7]);
    }
}

// ================= fallback multi-kernel path (proven R5, ~200us) =================

__global__ void prep_kernel(const float* __restrict__ x, const float* __restrict__ Wg,
                            const float* __restrict__ bg,
                            const float* __restrict__ W1, const float* __restrict__ W3,
                            const float* __restrict__ W2,
                            unsigned short* __restrict__ w1t, unsigned short* __restrict__ w3t,
                            unsigned short* __restrict__ w2t,
                            int* __restrict__ top_idx, float* __restrict__ top_p,
                            unsigned short* __restrict__ xb) {
    if (blockIdx.x < 3072) {
        __shared__ float tile[64][65];
        const int cb = blockIdx.x;
        const int wsel = cb >> 10;
        const float* src; unsigned short* dst; int K, N;
        if (wsel == 0)      { src = W1; dst = w1t; K = DM;  N = HID; }
        else if (wsel == 1) { src = W3; dst = w3t; K = DM;  N = HID; }
        else                { src = W2; dst = w2t; K = HID; N = DM;  }
        const int tkn = (K >> 6) * (N >> 6);
        int b = cb & 1023;
        int e = b / tkn;
        int rem = b % tkn;
        const int tn6 = N >> 6;
        int kt = rem / tn6, nt = rem % tn6;
        int tx = threadIdx.x & 15, ty = threadIdx.x >> 4;
        const float* s = src + ((size_t)(e * K + kt * 64 + ty)) * N + nt * 64 + tx * 4;
        #pragma unroll
        for (int i = 0; i < 4; i++) {
            float4 v = *(const float4*)(s + (size_t)(i * 16) * N);
            float* tr = &tile[ty + i * 16][tx * 4];
            tr[0] = v.x; tr[1] = v.y; tr[2] = v.z; tr[3] = v.w;
        }
        __syncthreads();
        int n = threadIdx.x >> 3;
        int c8 = (threadIdx.x & 7) * 8;
        unsigned short* d = dst + ((size_t)(e * N + nt * 64)) * K + kt * 64;
        #pragma unroll
        for (int i = 0; i < 2; i++) {
            int nn = n + i * 32;
            u16x8 r;
            #pragma unroll
            for (int kk = 0; kk < 8; kk++) r[kk] = f2bf(tile[c8 + kk][nn]);
            *(u16x8*)(d + (size_t)nn * K + c8) = r;
        }
    } else {
        int lane = threadIdx.x & 63, wave = threadIdx.x >> 6;
        int t = (blockIdx.x - 3072) * 4 + wave;
        float acc[NE];
        #pragma unroll
        for (int e = 0; e < NE; e++) acc[e] = 0.f;
        const float* xr = x + (size_t)t * DM;
        unsigned short* xbr = xb + (size_t)t * DM;
        #pragma unroll
        for (int j = 0; j < 8; j++) {
            int d = lane + j * 64;
            float xv = xr[d];
            xbr[d] = f2bf(xv);
            const float4* wr = (const float4*)(Wg + (size_t)d * NE);
            float4 w0 = wr[0], w1 = wr[1];
            acc[0] += xv * w0.x; acc[1] += xv * w0.y; acc[2] += xv * w0.z; acc[3] += xv * w0.w;
            acc[4] += xv * w1.x; acc[5] += xv * w1.y; acc[6] += xv * w1.z; acc[7] += xv * w1.w;
        }
        #pragma unroll
        for (int e = 0; e < NE; e++) {
            float v = acc[e];
            #pragma unroll
            for (int off = 32; off > 0; off >>= 1) v += __shfl_down(v, off, 64);
            acc[e] = v;
        }
        if (lane == 0) {
            float best = -1e30f, second = -1e30f;
            int bi = 0, si = 0;
            #pragma unroll
            for (int e = 0; e < NE; e++) {
                float v = acc[e] + bg[e];
                if (v > best) { second = best; si = bi; best = v; bi = e; }
                else if (v > second) { second = v; si = e; }
            }
            float ex = __expf(second - best);
            float inv = 1.f / (1.f + ex);
            top_idx[t * 2] = bi;  top_idx[t * 2 + 1] = si;
            top_p[t * 2] = inv;   top_p[t * 2 + 1] = ex * inv;
        }
    }
}

__global__ void hist_kernel(const int* __restrict__ top_idx, int* __restrict__ block_hist) {
    __shared__ int h[NE];
    int b = blockIdx.x, tid = threadIdx.x;
    if (tid < NE) h[tid] = 0;
    __syncthreads();
    int t = b * 256 + tid;
    atomicAdd(&h[top_idx[t * 2]], 1);
    atomicAdd(&h[top_idx[t * 2 + 1]], 1);
    __syncthreads();
    if (tid < NE) block_hist[b * NE + tid] = h[tid];
}

__global__ void prefix_kernel(const int* __restrict__ block_hist, int* __restrict__ counts,
                              int* __restrict__ offsets, int* __restrict__ bases) {
    int e = threadIdx.x;
    if (e < NE) {
        int run = 0;
        for (int b = 0; b < NB; b++) { bases[b * NE + e] = run; run += block_hist[b * NE + e]; }
        counts[e] = run;
    }
    __syncthreads();
    if (e == 0) {
        int s = 0;
        for (int ee = 0; ee < NE; ee++) { offsets[ee] = s; s += counts[ee]; }
    }
    __syncthreads();
    if (e < NE) {
        int off = offsets[e];
        for (int b = 0; b < NB; b++) bases[b * NE + e] += off;
    }
}

__global__ void build_kernel(const int* __restrict__ top_idx, const float* __restrict__ top_p,
                             const int* __restrict__ bases,
                             int* __restrict__ rows, float* __restrict__ gates,
                             int* __restrict__ slot_of) {
    __shared__ int cur[NE];
    int b = blockIdx.x, tid = threadIdx.x;
    if (tid < NE) cur[tid] = bases[b * NE + tid];
    __syncthreads();
    int t = b * 256 + tid;
    #pragma unroll
    for (int k = 0; k < 2; k++) {
        int e = top_idx[t * 2 + k];
        int slot = atomicAdd(&cur[e], 1);
        rows[slot] = t;
        gates[slot] = top_p[t * 2 + k];
        slot_of[t * 2 + k] = slot;
    }
}

__global__ __launch_bounds__(256) void gemm1_kernel(
    const unsigned short* __restrict__ xb, const unsigned short* __restrict__ w1t,
    const unsigned short* __restrict__ w3t, unsigned short* __restrict__ Hb,
    const int* __restrict__ rows, const int* __restrict__ counts,
    const int* __restrict__ offsets) {
    __shared__ Smem sm;
    gemm1_tile(blockIdx.x, sm, xb, w1t, w3t, Hb, rows, counts, offsets);
}

__global__ __launch_bounds__(256) void gemm2_kernel(
    const unsigned short* __restrict__ Hb, const unsigned short* __restrict__ w2t,
    unsigned short* __restrict__ P, const float* __restrict__ gates,
    const int* __restrict__ counts, const int* __restrict__ offsets) {
    __shared__ Smem sm;
    gemm2_tile(blockIdx.x, sm, Hb, w2t, P, gates, counts, offsets);
}

__global__ void combine_kernel(const unsigned short* __restrict__ P,
                               const int* __restrict__ slot_of, float* __restrict__ y) {
    int i = blockIdx.x * blockDim.x + threadIdx.x;
    int t = i / (DM / 8);
    int c8 = i % (DM / 8);
    int s0 = slot_of[t * 2], s1 = slot_of[t * 2 + 1];
    uint4 a = *(const uint4*)(P + (size_t)s0 * DM + c8 * 8);
    uint4 b = *(const uint4*)(P + (size_t)s1 * DM + c8 * 8);
    float o[8];
    const unsigned* aw = (const unsigned*)&a;
    const unsigned* bw = (const unsigned*)&b;
    #pragma unroll
    for (int j = 0; j < 4; j++) {
        union { unsigned u; float f; } al, ah, bl, bh;
        al.u = aw[j] << 16; ah.u = aw[j] & 0xffff0000u;
        bl.u = bw[j] << 16; bh.u = bw[j] & 0xffff0000u;
        o[j * 2]     = al.f + bl.f;
        o[j * 2 + 1] = ah.f + bh.f;
    }
    float4* yo = (float4*)(y + (size_t)t * DM + c8 * 8);
    yo[0] = make_float4(o[0], o[1], o[2], o[3]);
    yo[1] = make_float4(o[4], o[5], o[6], o[7]);
}

extern "C" void kernel_launch(void* const* d_in, const int* in_sizes, int n_in,
                              void* d_out, int out_size, void* d_ws, size_t ws_size,
                              hipStream_t stream) {
    (void)in_sizes; (void)n_in; (void)out_size; (void)ws_size;
    const float* x  = (const float*)d_in[0];
    const float* Wg = (const float*)d_in[1];
    const float* bg = (const float*)d_in[2];
    const float* W1 = (const float*)d_in[3];
    const float* W3 = (const float*)d_in[4];
    const float* W2 = (const float*)d_in[5];
    float* y = (float*)d_out;

    char* p = (char*)d_ws;
    auto carve = [&](size_t bytes) -> char* {
        char* r = p;
        p += (bytes + 255) & ~(size_t)255;
        return r;
    };
    unsigned short* w1t  = (unsigned short*)carve((size_t)NE * DM * HID * 2);   // 8 MB
    unsigned short* w3t  = (unsigned short*)carve((size_t)NE * DM * HID * 2);   // 8 MB (contiguous)
    unsigned short* w2t  = (unsigned short*)carve((size_t)NE * HID * DM * 2);
    unsigned short* xb   = (unsigned short*)carve((size_t)TOKENS * DM * 2);
    unsigned short* Hb   = (unsigned short*)carve((size_t)NSLOT * HID * 2);
    int*   rows    = (int*)carve(NSLOT * 4);
    float* gates   = (float*)carve(NSLOT * 4);
    int*   slot_of = (int*)carve(NSLOT * 4);
    int*   tidx    = (int*)carve((size_t)TOKENS * 2 * 4);
    float* tp      = (float*)carve((size_t)TOKENS * 2 * 4);
    int*   counts  = (int*)carve(256);
    int*   offsets = (int*)carve(256);
    int*   bhist   = (int*)carve((size_t)NB * NE * 4);
    int*   bases   = (int*)carve((size_t)NB * NE * 4);
    // P (bf16, 16 MB) aliases w1t+w3t (16 MB) — dead after gemm1 completes.
    unsigned short* P = w1t;

    // ---- preferred: single cooperative persistent kernel ----
    {
        const float* xa = x; const float* Wga = Wg; const float* bga = bg;
        const float* W1a = W1; const float* W3a = W3; const float* W2a = W2;
        unsigned short* w1ta = w1t; unsigned short* w3ta = w3t; unsigned short* w2ta = w2t;
        unsigned short* xba = xb; unsigned short* Hba = Hb;
        int* tidxa = tidx; float* tpa = tp; int* bhista = bhist;
        int* countsa = counts; int* offsetsa = offsets;
        int* rowsa = rows; float* gatesa = gates; int* slot_ofa = slot_of;
        unsigned short* Pa = P; float* ya = y;
        void* args[] = {
            &xa, &Wga, &bga, &W1a, &W3a, &W2a,
            &w1ta, &w3ta, &w2ta, &xba, &Hba,
            &tidxa, &tpa, &bhista, &countsa, &offsetsa,
            &rowsa, &gatesa, &slot_ofa, &Pa, &ya
        };
        hipError_t err = hipLaunchCooperativeKernel(
            (const void*)moe_mega, dim3(GRID), dim3(256), args, 0, stream);
        if (err == hipSuccess) return;
        (void)hipGetLastError();   // clear sticky error, fall through to multi-kernel path
    }

    // ---- fallback: proven R5 multi-kernel path ----
    prep_kernel<<<dim3(3072 + TOKENS / 4), dim3(256), 0, stream>>>(
        x, Wg, bg, W1, W3, W2, w1t, w3t, w2t, tidx, tp, xb);
    hist_kernel<<<dim3(NB), dim3(256), 0, stream>>>(tidx, bhist);
    prefix_kernel<<<dim3(1), dim3(64), 0, stream>>>(bhist, counts, offsets, bases);
    build_kernel<<<dim3(NB), dim3(256), 0, stream>>>(tidx, tp, bases, rows, gates, slot_of);
    gemm1_kernel<<<dim3((HID / BN) * MAXTILE), dim3(256), 0, stream>>>(xb, w1t, w3t, Hb, rows, counts, offsets);
    gemm2_kernel<<<dim3((DM / BN2) * MAXTILE), dim3(256), 0, stream>>>(Hb, w2t, P, gates, counts, offsets);
    combine_kernel<<<dim3((TOKENS * DM / 8) / 256), dim3(256), 0, stream>>>(P, slot_of, y);
}

// Round 9
// 198.378 us; speedup vs baseline: 6.2763x; 3.6090x over previous
//
#include <hip/hip_runtime.h>
#include <hip/hip_bf16.h>

#define TOKENS 8192
#define DM 512
#define NE 8
#define HID 1024
#define NSLOT (TOKENS * 2)
#define NB 32          // token blocks for hist/build (256 tokens each)

#define BM 128
#define BN 64
#define BK 64
#define BN2 128        // gemm2 N-tile
#define MAXTILE 136    // 8 * 17, > sum ceil(counts[e]/BM) worst case (135)

typedef __bf16 bf16x8 __attribute__((ext_vector_type(8)));
typedef float floatx4 __attribute__((ext_vector_type(4)));
typedef unsigned short u16x8 __attribute__((ext_vector_type(8)));

__device__ __forceinline__ unsigned short f2bf(float f) {
    union { float f; unsigned u; } c; c.f = f;
    unsigned u = c.u;
    u += 0x7fffu + ((u >> 16) & 1u);   // RNE
    return (unsigned short)(u >> 16);
}

// async global->LDS, 16B per lane, LDS dest = wave-uniform base + lane*16
__device__ __forceinline__ void load16_lds(const void* g, void* l) {
    __builtin_amdgcn_global_load_lds(
        (const __attribute__((address_space(1))) unsigned int*)g,
        (__attribute__((address_space(3))) unsigned int*)l, 16, 0, 0);
}

// ------- prep: fused weight-convert/transpose + router ----------------------
// blocks [0,3072): all 3 weights [E][K][N] fp32 -> [E][N][K] bf16 (64x64 tiles)
// blocks [3072,5120): router (fp32 logits, top-2, softmax over 2) + x->bf16.
// [R6-R8 post-mortem: ALL grid-wide sync mechanisms are off the table on this
// 8-XCD part — cooperative grid.sync() costs ~100us each (R7: kernel stretched
// 5.7x, work/traffic unchanged), and a hand-rolled atomic spin barrier hung
// the container (R8). Inter-phase ordering must come from kernel boundaries.]
__global__ void prep_kernel(const float* __restrict__ x, const float* __restrict__ Wg,
                            const float* __restrict__ bg,
                            const float* __restrict__ W1, const float* __restrict__ W3,
                            const float* __restrict__ W2,
                            unsigned short* __restrict__ w1t, unsigned short* __restrict__ w3t,
                            unsigned short* __restrict__ w2t,
                            int* __restrict__ top_idx, float* __restrict__ top_p,
                            unsigned short* __restrict__ xb) {
    if (blockIdx.x < 3072) {
        // ---------- cvt/transpose role ----------
        __shared__ float tile[64][65];
        const int cb = blockIdx.x;
        const int wsel = cb >> 10;               // 0,1,2
        const float* src; unsigned short* dst; int K, N;
        if (wsel == 0)      { src = W1; dst = w1t; K = DM;  N = HID; }
        else if (wsel == 1) { src = W3; dst = w3t; K = DM;  N = HID; }
        else                { src = W2; dst = w2t; K = HID; N = DM;  }
        const int tkn = (K >> 6) * (N >> 6);     // 128 for all three
        int b = cb & 1023;                       // 0 .. NE*tkn-1 (== 1024)
        int e = b / tkn;
        int rem = b % tkn;
        const int tn6 = N >> 6;
        int kt = rem / tn6, nt = rem % tn6;
        int tx = threadIdx.x & 15, ty = threadIdx.x >> 4;   // 16 x 16
        const float* s = src + ((size_t)(e * K + kt * 64 + ty)) * N + nt * 64 + tx * 4;
        #pragma unroll
        for (int i = 0; i < 4; i++) {
            float4 v = *(const float4*)(s + (size_t)(i * 16) * N);
            float* tr = &tile[ty + i * 16][tx * 4];
            tr[0] = v.x; tr[1] = v.y; tr[2] = v.z; tr[3] = v.w;
        }
        __syncthreads();
        int n = threadIdx.x >> 3;                // 0..31
        int c8 = (threadIdx.x & 7) * 8;          // k offset within tile
        unsigned short* d = dst + ((size_t)(e * N + nt * 64)) * K + kt * 64;
        #pragma unroll
        for (int i = 0; i < 2; i++) {
            int nn = n + i * 32;
            u16x8 r;
            #pragma unroll
            for (int kk = 0; kk < 8; kk++) r[kk] = f2bf(tile[c8 + kk][nn]);
            *(u16x8*)(d + (size_t)nn * K + c8) = r;
        }
    } else {
        // ---------- router role ----------
        int lane = threadIdx.x & 63, wave = threadIdx.x >> 6;
        int t = (blockIdx.x - 3072) * 4 + wave;
        float acc[NE];
        #pragma unroll
        for (int e = 0; e < NE; e++) acc[e] = 0.f;
        const float* xr = x + (size_t)t * DM;
        unsigned short* xbr = xb + (size_t)t * DM;
        #pragma unroll
        for (int j = 0; j < 8; j++) {
            int d = lane + j * 64;
            float xv = xr[d];
            xbr[d] = f2bf(xv);
            const float4* wr = (const float4*)(Wg + (size_t)d * NE);
            float4 w0 = wr[0], w1 = wr[1];
            acc[0] += xv * w0.x; acc[1] += xv * w0.y; acc[2] += xv * w0.z; acc[3] += xv * w0.w;
            acc[4] += xv * w1.x; acc[5] += xv * w1.y; acc[6] += xv * w1.z; acc[7] += xv * w1.w;
        }
        #pragma unroll
        for (int e = 0; e < NE; e++) {
            float v = acc[e];
            #pragma unroll
            for (int off = 32; off > 0; off >>= 1) v += __shfl_down(v, off, 64);
            acc[e] = v;
        }
        if (lane == 0) {
            float best = -1e30f, second = -1e30f;
            int bi = 0, si = 0;
            #pragma unroll
            for (int e = 0; e < NE; e++) {
                float v = acc[e] + bg[e];
                if (v > best) { second = best; si = bi; best = v; bi = e; }
                else if (v > second) { second = v; si = e; }
            }
            float ex = __expf(second - best);
            float inv = 1.f / (1.f + ex);
            top_idx[t * 2] = bi;  top_idx[t * 2 + 1] = si;
            top_p[t * 2] = inv;   top_p[t * 2 + 1] = ex * inv;
        }
    }
}

// ---------------- per-block LDS histogram ----------------
__global__ void hist_kernel(const int* __restrict__ top_idx, int* __restrict__ block_hist) {
    __shared__ int h[NE];
    int b = blockIdx.x, tid = threadIdx.x;
    if (tid < NE) h[tid] = 0;
    __syncthreads();
    int t = b * 256 + tid;
    atomicAdd(&h[top_idx[t * 2]], 1);
    atomicAdd(&h[top_idx[t * 2 + 1]], 1);
    __syncthreads();
    if (tid < NE) block_hist[b * NE + tid] = h[tid];
}

// ------- buildp: prefix + build fused (reads completed block_hist) ----------
// block_hist was finished by the PREVIOUS kernel node, so each of the 32
// blocks can recompute the global prefix locally (32x8 reads — the exact
// Phase-C math that passed correctness inside the R6/R7 mega kernel) with no
// cross-block sync. Block 0 publishes counts/offsets for the GEMMs.
__global__ void buildp_kernel(const int* __restrict__ top_idx, const float* __restrict__ top_p,
                              const int* __restrict__ block_hist,
                              int* __restrict__ counts, int* __restrict__ offsets,
                              int* __restrict__ rows, float* __restrict__ gates,
                              int* __restrict__ slot_of) {
    __shared__ int cnt[NE];
    __shared__ int mybase[NE];
    __shared__ int cur[NE];
    const int b = blockIdx.x, tid = threadIdx.x;
    if (tid < NE) {
        int run = 0, mb = 0;
        for (int bb = 0; bb < NB; bb++) {
            if (bb == b) mb = run;
            run += block_hist[bb * NE + tid];
        }
        cnt[tid] = run;
        mybase[tid] = mb;
    }
    __syncthreads();
    if (tid < NE) {
        int offs = 0;
        for (int ee = 0; ee < tid; ee++) offs += cnt[ee];
        cur[tid] = offs + mybase[tid];
        if (b == 0) { counts[tid] = cnt[tid]; offsets[tid] = offs; }
    }
    __syncthreads();
    const int t = b * 256 + tid;
    #pragma unroll
    for (int k = 0; k < 2; k++) {
        int e = top_idx[t * 2 + k];
        int slot = atomicAdd(&cur[e], 1);
        rows[slot] = t;
        gates[slot] = top_p[t * 2 + k];
        slot_of[t * 2 + k] = slot;
    }
}

// map compact tile id gy -> (expert e, tile mt); returns false past the end
__device__ __forceinline__ bool tile_lookup(const int* counts, const int* offsets, int gy,
                                            int& e, int& mt, int& cnt, int& off) {
    int bacc = 0;
    #pragma unroll
    for (int ee = 0; ee < NE; ee++) {
        int c = counts[ee];
        int ntl = (c + BM - 1) >> 7;
        if (gy < bacc + ntl) { e = ee; mt = gy - bacc; cnt = c; off = offsets[ee]; return true; }
        bacc += ntl;
    }
    return false;
}

// ---------------- GEMM1: H = silu(X*W1) .* (X*W3), bf16 out ----------------
// 128(slots) x 64(cols of BOTH W1,W3), BK=64, SINGLE-buffered global_load_lds
// (m97 structure): 32 KB LDS; cross-block TLP hides the vmcnt drain (occupancy
// is VGPR-bound at ~144 unified regs). Proven ~47.5 us / ~723 TF.
// [8-phase port and dbuf both regressed — see R2/R0 post-mortems.]
__global__ __launch_bounds__(256) void gemm1_kernel(
    const unsigned short* __restrict__ xb,     // [TOKENS][DM]
    const unsigned short* __restrict__ w1t,    // [E][HID][DM]
    const unsigned short* __restrict__ w3t,    // [E][HID][DM]
    unsigned short* __restrict__ Hb,           // [NSLOT][HID]
    const int* __restrict__ rows, const int* __restrict__ counts,
    const int* __restrict__ offsets) {
    const int lid = blockIdx.x;                // 0 .. 16*MAXTILE-1
    const int xcd = lid & 7;
    const int j = lid >> 3;                    // 0..271
    const int gy = xcd * (MAXTILE / 8) + (j >> 4);
    const int nt = j & 15;
    int e, mt, cnt, off;
    if (!tile_lookup(counts, offsets, gy, e, mt, cnt, off)) return;

    __shared__ unsigned short As[BM * BK];     // 16 KB
    __shared__ unsigned short B1s[BN * BK];    // 8 KB
    __shared__ unsigned short B3s[BN * BK];    // 8 KB

    const int tid = threadIdx.x;
    const int lane = tid & 63, wave = tid >> 6;
    const int lrow8 = lane >> 3;               // 0..7
    const int lchunk = (lane & 7) ^ lrow8;     // swizzled global chunk this lane fetches

    const unsigned short* a_g[4];
    #pragma unroll
    for (int i = 0; i < 4; i++) {
        int r = (wave * 4 + i) * 8 + lrow8;    // 0..127
        int gr = mt * BM + r;
        int tok = rows[off + (gr < cnt ? gr : 0)];
        a_g[i] = xb + (size_t)tok * DM + lchunk * 8;
    }
    const unsigned short* b1_g[2]; const unsigned short* b3_g[2];
    #pragma unroll
    for (int i = 0; i < 2; i++) {
        int r = (wave * 2 + i) * 8 + lrow8;    // 0..63
        b1_g[i] = w1t + ((size_t)e * HID + nt * BN + r) * DM + lchunk * 8;
        b3_g[i] = w3t + ((size_t)e * HID + nt * BN + r) * DM + lchunk * 8;
    }

    const int l15 = lane & 15, quad = lane >> 4;
    const int sw = l15 & 7;

    floatx4 acc1[2][4], acc3[2][4];
    #pragma unroll
    for (int i = 0; i < 2; i++)
        #pragma unroll
        for (int j2 = 0; j2 < 4; j2++) {
            acc1[i][j2] = (floatx4){0.f, 0.f, 0.f, 0.f};
            acc3[i][j2] = (floatx4){0.f, 0.f, 0.f, 0.f};
        }

    auto stage = [&](int k0) {
        #pragma unroll
        for (int i = 0; i < 4; i++) load16_lds(a_g[i] + k0, &As[(wave * 4 + i) * 512]);
        #pragma unroll
        for (int i = 0; i < 2; i++) {
            load16_lds(b1_g[i] + k0, &B1s[(wave * 2 + i) * 512]);
            load16_lds(b3_g[i] + k0, &B3s[(wave * 2 + i) * 512]);
        }
    };
    auto compute = [&]() {
        #pragma unroll
        for (int kk = 0; kk < 2; kk++) {
            const int qc = kk * 4 + quad;
            const int ch = (qc ^ sw) << 3;
            bf16x8 af[2], b1f[4], b3f[4];
            #pragma unroll
            for (int mi = 0; mi < 2; mi++)
                af[mi] = *(const bf16x8*)(&As[(wave * 32 + mi * 16 + l15) * 64 + ch]);
            #pragma unroll
            for (int ni = 0; ni < 4; ni++) {
                b1f[ni] = *(const bf16x8*)(&B1s[(ni * 16 + l15) * 64 + ch]);
                b3f[ni] = *(const bf16x8*)(&B3s[(ni * 16 + l15) * 64 + ch]);
            }
            #pragma unroll
            for (int mi = 0; mi < 2; mi++)
                #pragma unroll
                for (int ni = 0; ni < 4; ni++) {
                    acc1[mi][ni] = __builtin_amdgcn_mfma_f32_16x16x32_bf16(af[mi], b1f[ni], acc1[mi][ni], 0, 0, 0);
                    acc3[mi][ni] = __builtin_amdgcn_mfma_f32_16x16x32_bf16(af[mi], b3f[ni], acc3[mi][ni], 0, 0, 0);
                }
        }
    };

    const int NI = DM / BK;   // 8
    #pragma unroll
    for (int i = 0; i < NI; i++) {
        if (i) __syncthreads();               // prior reads of LDS done before overwrite
        stage(i * BK);
        __syncthreads();                      // vmcnt drained: tile staged
        compute();
    }
    // epilogue: silu(z1)*z3 -> bf16; C/D: col=l15, row=quad*4+r
    #pragma unroll
    for (int mi = 0; mi < 2; mi++) {
        #pragma unroll
        for (int r = 0; r < 4; r++) {
            int mloc = wave * 32 + mi * 16 + quad * 4 + r;
            int gi = mt * BM + mloc;
            if (gi < cnt) {
                size_t rowbase = (size_t)(off + gi) * HID + nt * BN;
                #pragma unroll
                for (int ni = 0; ni < 4; ni++) {
                    float z1 = acc1[mi][ni][r];
                    float z3 = acc3[mi][ni][r];
                    float h = (z1 / (1.f + __expf(-z1))) * z3;
                    Hb[rowbase + ni * 16 + l15] = f2bf(h);
                }
            }
        }
    }
}

// ------- GEMM2: P[slot] = bf16(gates[slot] * (H[slot] @ W2)) — no atomics --------
// BN2=128: 128x128 tile, As 16K + Bs 16K = 32 KB single-buffered (proven R5).
__global__ __launch_bounds__(256) void gemm2_kernel(
    const unsigned short* __restrict__ Hb,    // [NSLOT][HID]
    const unsigned short* __restrict__ w2t,   // [E][DM][HID]
    unsigned short* __restrict__ P,           // [NSLOT][DM] bf16, gated
    const float* __restrict__ gates,
    const int* __restrict__ counts, const int* __restrict__ offsets) {
    const int lid = blockIdx.x;                // 0 .. 4*MAXTILE-1
    const int xcd = lid & 7;
    const int j = lid >> 3;                    // 0..67
    const int gy = xcd * (MAXTILE / 8) + (j >> 2);
    const int nt = j & 3;                      // 4 col-groups of 128
    int e, mt, cnt, off;
    if (!tile_lookup(counts, offsets, gy, e, mt, cnt, off)) return;

    __shared__ unsigned short As[BM * BK];     // 16 KB
    __shared__ unsigned short Bs[BN2 * BK];    // 16 KB

    const int tid = threadIdx.x;
    const int lane = tid & 63, wave = tid >> 6;
    const int lrow8 = lane >> 3;
    const int lchunk = (lane & 7) ^ lrow8;

    const unsigned short* a_g[4];
    #pragma unroll
    for (int i = 0; i < 4; i++) {
        int r = (wave * 4 + i) * 8 + lrow8;    // 0..127
        int sl = off + mt * BM + r;
        if (sl >= NSLOT) sl = NSLOT - 1;      // clamp (ragged tail), value unused
        a_g[i] = Hb + (size_t)sl * HID + lchunk * 8;
    }
    const unsigned short* b_g[4];
    #pragma unroll
    for (int i = 0; i < 4; i++) {
        int r = (wave * 4 + i) * 8 + lrow8;    // 0..127
        b_g[i] = w2t + ((size_t)e * DM + nt * BN2 + r) * HID + lchunk * 8;
    }

    const int l15 = lane & 15, quad = lane >> 4;
    const int sw = l15 & 7;

    floatx4 acc[2][8];
    #pragma unroll
    for (int i = 0; i < 2; i++)
        #pragma unroll
        for (int j2 = 0; j2 < 8; j2++) acc[i][j2] = (floatx4){0.f, 0.f, 0.f, 0.f};

    auto stage = [&](int k0) {
        #pragma unroll
        for (int i = 0; i < 4; i++) load16_lds(a_g[i] + k0, &As[(wave * 4 + i) * 512]);
        #pragma unroll
        for (int i = 0; i < 4; i++) load16_lds(b_g[i] + k0, &Bs[(wave * 4 + i) * 512]);
    };
    auto compute = [&]() {
        #pragma unroll
        for (int kk = 0; kk < 2; kk++) {
            const int qc = kk * 4 + quad;
            const int ch = (qc ^ sw) << 3;
            bf16x8 af[2], bf[8];
            #pragma unroll
            for (int mi = 0; mi < 2; mi++)
                af[mi] = *(const bf16x8*)(&As[(wave * 32 + mi * 16 + l15) * 64 + ch]);
            #pragma unroll
            for (int ni = 0; ni < 8; ni++)
                bf[ni] = *(const bf16x8*)(&Bs[(ni * 16 + l15) * 64 + ch]);
            #pragma unroll
            for (int mi = 0; mi < 2; mi++)
                #pragma unroll
                for (int ni = 0; ni < 8; ni++)
                    acc[mi][ni] = __builtin_amdgcn_mfma_f32_16x16x32_bf16(af[mi], bf[ni], acc[mi][ni], 0, 0, 0);
        }
    };

    const int NI = HID / BK;   // 16
    #pragma unroll
    for (int i = 0; i < NI; i++) {
        if (i) __syncthreads();
        stage(i * BK);
        __syncthreads();
        compute();
    }
    #pragma unroll
    for (int mi = 0; mi < 2; mi++) {
        #pragma unroll
        for (int r = 0; r < 4; r++) {
            int mloc = wave * 32 + mi * 16 + quad * 4 + r;
            int gi = mt * BM + mloc;
            if (gi < cnt) {
                int slot = off + gi;
                float g = gates[slot];
                #pragma unroll
                for (int ni = 0; ni < 8; ni++) {
                    int col = nt * BN2 + ni * 16 + l15;
                    P[(size_t)slot * DM + col] = f2bf(g * acc[mi][ni][r]);
                }
            }
        }
    }
}

// ---------------- combine: y[t] = P[s0] + P[s1] (P bf16, pre-gated) ----------------
__global__ void combine_kernel(const unsigned short* __restrict__ P,
                               const int* __restrict__ slot_of, float* __restrict__ y) {
    int i = blockIdx.x * blockDim.x + threadIdx.x;    // per 8 elems
    int t = i / (DM / 8);
    int c8 = i % (DM / 8);
    int s0 = slot_of[t * 2], s1 = slot_of[t * 2 + 1];
    uint4 a = *(const uint4*)(P + (size_t)s0 * DM + c8 * 8);
    uint4 b = *(const uint4*)(P + (size_t)s1 * DM + c8 * 8);
    float o[8];
    const unsigned* aw = (const unsigned*)&a;
    const unsigned* bw = (const unsigned*)&b;
    #pragma unroll
    for (int j = 0; j < 4; j++) {
        union { unsigned u; float f; } al, ah, bl, bh;
        al.u = aw[j] << 16; ah.u = aw[j] & 0xffff0000u;
        bl.u = bw[j] << 16; bh.u = bw[j] & 0xffff0000u;
        o[j * 2]     = al.f + bl.f;
        o[j * 2 + 1] = ah.f + bh.f;
    }
    float4* yo = (float4*)(y + (size_t)t * DM + c8 * 8);
    yo[0] = make_float4(o[0], o[1], o[2], o[3]);
    yo[1] = make_float4(o[4], o[5], o[6], o[7]);
}

extern "C" void kernel_launch(void* const* d_in, const int* in_sizes, int n_in,
                              void* d_out, int out_size, void* d_ws, size_t ws_size,
                              hipStream_t stream) {
    (void)in_sizes; (void)n_in; (void)out_size; (void)ws_size;
    const float* x  = (const float*)d_in[0];
    const float* Wg = (const float*)d_in[1];
    const float* bg = (const float*)d_in[2];
    const float* W1 = (const float*)d_in[3];
    const float* W3 = (const float*)d_in[4];
    const float* W2 = (const float*)d_in[5];
    float* y = (float*)d_out;

    char* p = (char*)d_ws;
    auto carve = [&](size_t bytes) -> char* {
        char* r = p;
        p += (bytes + 255) & ~(size_t)255;
        return r;
    };
    unsigned short* w1t  = (unsigned short*)carve((size_t)NE * DM * HID * 2);   // 8 MB
    unsigned short* w3t  = (unsigned short*)carve((size_t)NE * DM * HID * 2);   // 8 MB (contiguous)
    unsigned short* w2t  = (unsigned short*)carve((size_t)NE * HID * DM * 2);
    unsigned short* xb   = (unsigned short*)carve((size_t)TOKENS * DM * 2);
    unsigned short* Hb   = (unsigned short*)carve((size_t)NSLOT * HID * 2);
    int*   rows    = (int*)carve(NSLOT * 4);
    float* gates   = (float*)carve(NSLOT * 4);
    int*   slot_of = (int*)carve(NSLOT * 4);
    int*   tidx    = (int*)carve((size_t)TOKENS * 2 * 4);
    float* tp      = (float*)carve((size_t)TOKENS * 2 * 4);
    int*   counts  = (int*)carve(256);
    int*   offsets = (int*)carve(256);
    int*   bhist   = (int*)carve((size_t)NB * NE * 4);
    // P (bf16, 16 MB) aliases w1t+w3t (16 MB) — dead after gemm1 completes.
    unsigned short* P = w1t;

    prep_kernel<<<dim3(3072 + TOKENS / 4), dim3(256), 0, stream>>>(
        x, Wg, bg, W1, W3, W2, w1t, w3t, w2t, tidx, tp, xb);
    hist_kernel<<<dim3(NB), dim3(256), 0, stream>>>(tidx, bhist);
    buildp_kernel<<<dim3(NB), dim3(256), 0, stream>>>(
        tidx, tp, bhist, counts, offsets, rows, gates, slot_of);
    gemm1_kernel<<<dim3((HID / BN) * MAXTILE), dim3(256), 0, stream>>>(xb, w1t, w3t, Hb, rows, counts, offsets);
    gemm2_kernel<<<dim3((DM / BN2) * MAXTILE), dim3(256), 0, stream>>>(Hb, w2t, P, gates, counts, offsets);
    combine_kernel<<<dim3((TOKENS * DM / 8) / 256), dim3(256), 0, stream>>>(P, slot_of, y);
}

// Round 10
// 197.167 us; speedup vs baseline: 6.3148x; 1.0061x over previous
//
#include <hip/hip_runtime.h>
#include <hip/hip_bf16.h>

#define TOKENS 8192
#define DM 512
#define NE 8
#define HID 1024
#define NSLOT (TOKENS * 2)
#define NB 32          // token chunks for sortbuild (256 tokens each)

#define BM 128
#define BN 64
#define BK 64
#define BN2 128        // gemm2 N-tile
#define MAXTILE 136    // 8 * 17, > sum ceil(counts[e]/BM) worst case (135)

typedef __bf16 bf16x8 __attribute__((ext_vector_type(8)));
typedef float floatx4 __attribute__((ext_vector_type(4)));
typedef unsigned short u16x8 __attribute__((ext_vector_type(8)));

__device__ __forceinline__ unsigned short f2bf(float f) {
    union { float f; unsigned u; } c; c.f = f;
    unsigned u = c.u;
    u += 0x7fffu + ((u >> 16) & 1u);   // RNE
    return (unsigned short)(u >> 16);
}

// async global->LDS, 16B per lane, LDS dest = wave-uniform base + lane*16
__device__ __forceinline__ void load16_lds(const void* g, void* l) {
    __builtin_amdgcn_global_load_lds(
        (const __attribute__((address_space(1))) unsigned int*)g,
        (__attribute__((address_space(3))) unsigned int*)l, 16, 0, 0);
}

// ------- prep: fused weight-convert/transpose + router ----------------------
// blocks [0,3072): all 3 weights [E][K][N] fp32 -> [E][N][K] bf16 (64x64 tiles)
// blocks [3072,5120): router (fp32 logits, top-2, softmax over 2) + x->bf16.
// [R6-R8 post-mortem: ALL grid-wide sync mechanisms are off the table on this
// 8-XCD part — cooperative grid.sync() costs ~100us each (R7), and a
// hand-rolled atomic spin barrier hung the container (R8). Inter-phase
// ordering comes from kernel boundaries only (~2-5us each, measured R9).]
__global__ void prep_kernel(const float* __restrict__ x, const float* __restrict__ Wg,
                            const float* __restrict__ bg,
                            const float* __restrict__ W1, const float* __restrict__ W3,
                            const float* __restrict__ W2,
                            unsigned short* __restrict__ w1t, unsigned short* __restrict__ w3t,
                            unsigned short* __restrict__ w2t,
                            int* __restrict__ top_idx, float* __restrict__ top_p,
                            unsigned short* __restrict__ xb) {
    if (blockIdx.x < 3072) {
        // ---------- cvt/transpose role ----------
        __shared__ float tile[64][65];
        const int cb = blockIdx.x;
        const int wsel = cb >> 10;               // 0,1,2
        const float* src; unsigned short* dst; int K, N;
        if (wsel == 0)      { src = W1; dst = w1t; K = DM;  N = HID; }
        else if (wsel == 1) { src = W3; dst = w3t; K = DM;  N = HID; }
        else                { src = W2; dst = w2t; K = HID; N = DM;  }
        const int tkn = (K >> 6) * (N >> 6);     // 128 for all three
        int b = cb & 1023;                       // 0 .. NE*tkn-1 (== 1024)
        int e = b / tkn;
        int rem = b % tkn;
        const int tn6 = N >> 6;
        int kt = rem / tn6, nt = rem % tn6;
        int tx = threadIdx.x & 15, ty = threadIdx.x >> 4;   // 16 x 16
        const float* s = src + ((size_t)(e * K + kt * 64 + ty)) * N + nt * 64 + tx * 4;
        #pragma unroll
        for (int i = 0; i < 4; i++) {
            float4 v = *(const float4*)(s + (size_t)(i * 16) * N);
            float* tr = &tile[ty + i * 16][tx * 4];
            tr[0] = v.x; tr[1] = v.y; tr[2] = v.z; tr[3] = v.w;
        }
        __syncthreads();
        int n = threadIdx.x >> 3;                // 0..31
        int c8 = (threadIdx.x & 7) * 8;          // k offset within tile
        unsigned short* d = dst + ((size_t)(e * N + nt * 64)) * K + kt * 64;
        #pragma unroll
        for (int i = 0; i < 2; i++) {
            int nn = n + i * 32;
            u16x8 r;
            #pragma unroll
            for (int kk = 0; kk < 8; kk++) r[kk] = f2bf(tile[c8 + kk][nn]);
            *(u16x8*)(d + (size_t)nn * K + c8) = r;
        }
    } else {
        // ---------- router role ----------
        int lane = threadIdx.x & 63, wave = threadIdx.x >> 6;
        int t = (blockIdx.x - 3072) * 4 + wave;
        float acc[NE];
        #pragma unroll
        for (int e = 0; e < NE; e++) acc[e] = 0.f;
        const float* xr = x + (size_t)t * DM;
        unsigned short* xbr = xb + (size_t)t * DM;
        #pragma unroll
        for (int j = 0; j < 8; j++) {
            int d = lane + j * 64;
            float xv = xr[d];
            xbr[d] = f2bf(xv);
            const float4* wr = (const float4*)(Wg + (size_t)d * NE);
            float4 w0 = wr[0], w1 = wr[1];
            acc[0] += xv * w0.x; acc[1] += xv * w0.y; acc[2] += xv * w0.z; acc[3] += xv * w0.w;
            acc[4] += xv * w1.x; acc[5] += xv * w1.y; acc[6] += xv * w1.z; acc[7] += xv * w1.w;
        }
        #pragma unroll
        for (int e = 0; e < NE; e++) {
            float v = acc[e];
            #pragma unroll
            for (int off = 32; off > 0; off >>= 1) v += __shfl_down(v, off, 64);
            acc[e] = v;
        }
        if (lane == 0) {
            float best = -1e30f, second = -1e30f;
            int bi = 0, si = 0;
            #pragma unroll
            for (int e = 0; e < NE; e++) {
                float v = acc[e] + bg[e];
                if (v > best) { second = best; si = bi; best = v; bi = e; }
                else if (v > second) { second = v; si = e; }
            }
            float ex = __expf(second - best);
            float inv = 1.f / (1.f + ex);
            top_idx[t * 2] = bi;  top_idx[t * 2 + 1] = si;
            top_p[t * 2] = inv;   top_p[t * 2 + 1] = ex * inv;
        }
    }
}

// ------- sortbuild: hist + prefix + build in ONE node, NO cross-block dep ----
// Each of the 32 blocks redundantly scans ALL 16K top_idx entries (128 KB,
// L2-resident) accumulating per-thread PACKED 8x8-bit expert counters:
//   aAll  — all tokens (per-field max 64 iters x 2 = 128 < 256, no overflow)
//   aBef  — tokens in chunks < b  (k < b is wave-uniform)
// Unpack to 16-bit fields (wave-sum max 64x128 = 8192 < 65536), 6-step
// __shfl_down reduce, lane-0 merges into LDS. Gives each block global counts
// AND its own slot base with zero inter-block communication — the dependency
// that previously forced hist/prefix/build into 3 nodes (or a barrier).
__global__ void sortbuild_kernel(const int* __restrict__ top_idx, const float* __restrict__ top_p,
                                 int* __restrict__ counts, int* __restrict__ offsets,
                                 int* __restrict__ rows, float* __restrict__ gates,
                                 int* __restrict__ slot_of) {
    __shared__ int cntAll[NE], cntBef[NE], cur[NE];
    const int b = blockIdx.x, tid = threadIdx.x;
    const int lane = tid & 63;
    if (tid < NE) { cntAll[tid] = 0; cntBef[tid] = 0; }
    __syncthreads();

    unsigned long long aAll = 0ull, aBef = 0ull;
    for (int k = 0; k < TOKENS / 256; k++) {       // 32 iterations
        int t = k * 256 + tid;
        int2 ei = *(const int2*)(top_idx + (size_t)t * 2);
        unsigned long long inc = (1ull << (ei.x * 8)) + (1ull << (ei.y * 8));
        aAll += inc;
        if (k < b) aBef += inc;                    // wave-uniform predicate
    }
    // unpack 8x8-bit -> two 4x16-bit (lo: e0..e3, hi: e4..e7)
    auto unpackLo = [](unsigned long long a) {
        return ( a        & 0xFFull)        | ((( a >> 8 ) & 0xFFull) << 16)
             | (((a >> 16) & 0xFFull) << 32) | ((( a >> 24) & 0xFFull) << 48);
    };
    auto unpackHi = [](unsigned long long a) {
        return ((a >> 32) & 0xFFull)        | ((( a >> 40) & 0xFFull) << 16)
             | (((a >> 48) & 0xFFull) << 32) | ((( a >> 56) & 0xFFull) << 48);
    };
    unsigned long long sAllLo = unpackLo(aAll), sAllHi = unpackHi(aAll);
    unsigned long long sBefLo = unpackLo(aBef), sBefHi = unpackHi(aBef);
    #pragma unroll
    for (int off = 32; off > 0; off >>= 1) {
        sAllLo += __shfl_down(sAllLo, off, 64);
        sAllHi += __shfl_down(sAllHi, off, 64);
        sBefLo += __shfl_down(sBefLo, off, 64);
        sBefHi += __shfl_down(sBefHi, off, 64);
    }
    if (lane == 0) {
        #pragma unroll
        for (int e = 0; e < 4; e++) {
            atomicAdd(&cntAll[e],     (int)((sAllLo >> (e * 16)) & 0xFFFF));
            atomicAdd(&cntAll[e + 4], (int)((sAllHi >> (e * 16)) & 0xFFFF));
            atomicAdd(&cntBef[e],     (int)((sBefLo >> (e * 16)) & 0xFFFF));
            atomicAdd(&cntBef[e + 4], (int)((sBefHi >> (e * 16)) & 0xFFFF));
        }
    }
    __syncthreads();
    if (tid < NE) {
        int offs = 0;
        for (int ee = 0; ee < tid; ee++) offs += cntAll[ee];
        cur[tid] = offs + cntBef[tid];
        if (b == 0) { counts[tid] = cntAll[tid]; offsets[tid] = offs; }
    }
    __syncthreads();
    const int t = b * 256 + tid;
    #pragma unroll
    for (int k = 0; k < 2; k++) {
        int e = top_idx[t * 2 + k];
        int slot = atomicAdd(&cur[e], 1);
        rows[slot] = t;
        gates[slot] = top_p[t * 2 + k];
        slot_of[t * 2 + k] = slot;
    }
}

// map compact tile id gy -> (expert e, tile mt); returns false past the end
__device__ __forceinline__ bool tile_lookup(const int* counts, const int* offsets, int gy,
                                            int& e, int& mt, int& cnt, int& off) {
    int bacc = 0;
    #pragma unroll
    for (int ee = 0; ee < NE; ee++) {
        int c = counts[ee];
        int ntl = (c + BM - 1) >> 7;
        if (gy < bacc + ntl) { e = ee; mt = gy - bacc; cnt = c; off = offsets[ee]; return true; }
        bacc += ntl;
    }
    return false;
}

// ---------------- GEMM1: H = silu(X*W1) .* (X*W3), bf16 out ----------------
// 128(slots) x 64(cols of BOTH W1,W3), BK=64, SINGLE-buffered global_load_lds
// (m97 structure): 32 KB LDS; cross-block TLP hides the vmcnt drain.
// Proven ~47.5 us / ~723 TF with xb at workspace offset 0 (R5). [R9: moving
// weights to offset 0 coincided with FETCH 23.2->27.9 MB and 47.5->61 us —
// carve order restored to R5's this round to test the L2-aliasing theory.]
__global__ __launch_bounds__(256) void gemm1_kernel(
    const unsigned short* __restrict__ xb,     // [TOKENS][DM]
    const unsigned short* __restrict__ w1t,    // [E][HID][DM]
    const unsigned short* __restrict__ w3t,    // [E][HID][DM]
    unsigned short* __restrict__ Hb,           // [NSLOT][HID]
    const int* __restrict__ rows, const int* __restrict__ counts,
    const int* __restrict__ offsets) {
    const int lid = blockIdx.x;                // 0 .. 16*MAXTILE-1
    const int xcd = lid & 7;
    const int j = lid >> 3;                    // 0..271
    const int gy = xcd * (MAXTILE / 8) + (j >> 4);
    const int nt = j & 15;
    int e, mt, cnt, off;
    if (!tile_lookup(counts, offsets, gy, e, mt, cnt, off)) return;

    __shared__ unsigned short As[BM * BK];     // 16 KB
    __shared__ unsigned short B1s[BN * BK];    // 8 KB
    __shared__ unsigned short B3s[BN * BK];    // 8 KB

    const int tid = threadIdx.x;
    const int lane = tid & 63, wave = tid >> 6;
    const int lrow8 = lane >> 3;               // 0..7
    const int lchunk = (lane & 7) ^ lrow8;     // swizzled global chunk this lane fetches

    const unsigned short* a_g[4];
    #pragma unroll
    for (int i = 0; i < 4; i++) {
        int r = (wave * 4 + i) * 8 + lrow8;    // 0..127
        int gr = mt * BM + r;
        int tok = rows[off + (gr < cnt ? gr : 0)];
        a_g[i] = xb + (size_t)tok * DM + lchunk * 8;
    }
    const unsigned short* b1_g[2]; const unsigned short* b3_g[2];
    #pragma unroll
    for (int i = 0; i < 2; i++) {
        int r = (wave * 2 + i) * 8 + lrow8;    // 0..63
        b1_g[i] = w1t + ((size_t)e * HID + nt * BN + r) * DM + lchunk * 8;
        b3_g[i] = w3t + ((size_t)e * HID + nt * BN + r) * DM + lchunk * 8;
    }

    const int l15 = lane & 15, quad = lane >> 4;
    const int sw = l15 & 7;

    floatx4 acc1[2][4], acc3[2][4];
    #pragma unroll
    for (int i = 0; i < 2; i++)
        #pragma unroll
        for (int j2 = 0; j2 < 4; j2++) {
            acc1[i][j2] = (floatx4){0.f, 0.f, 0.f, 0.f};
            acc3[i][j2] = (floatx4){0.f, 0.f, 0.f, 0.f};
        }

    auto stage = [&](int k0) {
        #pragma unroll
        for (int i = 0; i < 4; i++) load16_lds(a_g[i] + k0, &As[(wave * 4 + i) * 512]);
        #pragma unroll
        for (int i = 0; i < 2; i++) {
            load16_lds(b1_g[i] + k0, &B1s[(wave * 2 + i) * 512]);
            load16_lds(b3_g[i] + k0, &B3s[(wave * 2 + i) * 512]);
        }
    };
    auto compute = [&]() {
        #pragma unroll
        for (int kk = 0; kk < 2; kk++) {
            const int qc = kk * 4 + quad;
            const int ch = (qc ^ sw) << 3;
            bf16x8 af[2], b1f[4], b3f[4];
            #pragma unroll
            for (int mi = 0; mi < 2; mi++)
                af[mi] = *(const bf16x8*)(&As[(wave * 32 + mi * 16 + l15) * 64 + ch]);
            #pragma unroll
            for (int ni = 0; ni < 4; ni++) {
                b1f[ni] = *(const bf16x8*)(&B1s[(ni * 16 + l15) * 64 + ch]);
                b3f[ni] = *(const bf16x8*)(&B3s[(ni * 16 + l15) * 64 + ch]);
            }
            #pragma unroll
            for (int mi = 0; mi < 2; mi++)
                #pragma unroll
                for (int ni = 0; ni < 4; ni++) {
                    acc1[mi][ni] = __builtin_amdgcn_mfma_f32_16x16x32_bf16(af[mi], b1f[ni], acc1[mi][ni], 0, 0, 0);
                    acc3[mi][ni] = __builtin_amdgcn_mfma_f32_16x16x32_bf16(af[mi], b3f[ni], acc3[mi][ni], 0, 0, 0);
                }
        }
    };

    const int NI = DM / BK;   // 8
    #pragma unroll
    for (int i = 0; i < NI; i++) {
        if (i) __syncthreads();               // prior reads of LDS done before overwrite
        stage(i * BK);
        __syncthreads();                      // vmcnt drained: tile staged
        compute();
    }
    // epilogue: silu(z1)*z3 -> bf16; C/D: col=l15, row=quad*4+r
    #pragma unroll
    for (int mi = 0; mi < 2; mi++) {
        #pragma unroll
        for (int r = 0; r < 4; r++) {
            int mloc = wave * 32 + mi * 16 + quad * 4 + r;
            int gi = mt * BM + mloc;
            if (gi < cnt) {
                size_t rowbase = (size_t)(off + gi) * HID + nt * BN;
                #pragma unroll
                for (int ni = 0; ni < 4; ni++) {
                    float z1 = acc1[mi][ni][r];
                    float z3 = acc3[mi][ni][r];
                    float h = (z1 / (1.f + __expf(-z1))) * z3;
                    Hb[rowbase + ni * 16 + l15] = f2bf(h);
                }
            }
        }
    }
}

// ------- GEMM2: P[slot] = bf16(gates[slot] * (H[slot] @ W2)) — no atomics --------
// BN2=128: 128x128 tile, As 16K + Bs 16K = 32 KB single-buffered (proven R5).
__global__ __launch_bounds__(256) void gemm2_kernel(
    const unsigned short* __restrict__ Hb,    // [NSLOT][HID]
    const unsigned short* __restrict__ w2t,   // [E][DM][HID]
    unsigned short* __restrict__ P,           // [NSLOT][DM] bf16, gated
    const float* __restrict__ gates,
    const int* __restrict__ counts, const int* __restrict__ offsets) {
    const int lid = blockIdx.x;                // 0 .. 4*MAXTILE-1
    const int xcd = lid & 7;
    const int j = lid >> 3;                    // 0..67
    const int gy = xcd * (MAXTILE / 8) + (j >> 2);
    const int nt = j & 3;                      // 4 col-groups of 128
    int e, mt, cnt, off;
    if (!tile_lookup(counts, offsets, gy, e, mt, cnt, off)) return;

    __shared__ unsigned short As[BM * BK];     // 16 KB
    __shared__ unsigned short Bs[BN2 * BK];    // 16 KB

    const int tid = threadIdx.x;
    const int lane = tid & 63, wave = tid >> 6;
    const int lrow8 = lane >> 3;
    const int lchunk = (lane & 7) ^ lrow8;

    const unsigned short* a_g[4];
    #pragma unroll
    for (int i = 0; i < 4; i++) {
        int r = (wave * 4 + i) * 8 + lrow8;    // 0..127
        int sl = off + mt * BM + r;
        if (sl >= NSLOT) sl = NSLOT - 1;      // clamp (ragged tail), value unused
        a_g[i] = Hb + (size_t)sl * HID + lchunk * 8;
    }
    const unsigned short* b_g[4];
    #pragma unroll
    for (int i = 0; i < 4; i++) {
        int r = (wave * 4 + i) * 8 + lrow8;    // 0..127
        b_g[i] = w2t + ((size_t)e * DM + nt * BN2 + r) * HID + lchunk * 8;
    }

    const int l15 = lane & 15, quad = lane >> 4;
    const int sw = l15 & 7;

    floatx4 acc[2][8];
    #pragma unroll
    for (int i = 0; i < 2; i++)
        #pragma unroll
        for (int j2 = 0; j2 < 8; j2++) acc[i][j2] = (floatx4){0.f, 0.f, 0.f, 0.f};

    auto stage = [&](int k0) {
        #pragma unroll
        for (int i = 0; i < 4; i++) load16_lds(a_g[i] + k0, &As[(wave * 4 + i) * 512]);
        #pragma unroll
        for (int i = 0; i < 4; i++) load16_lds(b_g[i] + k0, &Bs[(wave * 4 + i) * 512]);
    };
    auto compute = [&]() {
        #pragma unroll
        for (int kk = 0; kk < 2; kk++) {
            const int qc = kk * 4 + quad;
            const int ch = (qc ^ sw) << 3;
            bf16x8 af[2], bf[8];
            #pragma unroll
            for (int mi = 0; mi < 2; mi++)
                af[mi] = *(const bf16x8*)(&As[(wave * 32 + mi * 16 + l15) * 64 + ch]);
            #pragma unroll
            for (int ni = 0; ni < 8; ni++)
                bf[ni] = *(const bf16x8*)(&Bs[(ni * 16 + l15) * 64 + ch]);
            #pragma unroll
            for (int mi = 0; mi < 2; mi++)
                #pragma unroll
                for (int ni = 0; ni < 8; ni++)
                    acc[mi][ni] = __builtin_amdgcn_mfma_f32_16x16x32_bf16(af[mi], bf[ni], acc[mi][ni], 0, 0, 0);
        }
    };

    const int NI = HID / BK;   // 16
    #pragma unroll
    for (int i = 0; i < NI; i++) {
        if (i) __syncthreads();
        stage(i * BK);
        __syncthreads();
        compute();
    }
    #pragma unroll
    for (int mi = 0; mi < 2; mi++) {
        #pragma unroll
        for (int r = 0; r < 4; r++) {
            int mloc = wave * 32 + mi * 16 + quad * 4 + r;
            int gi = mt * BM + mloc;
            if (gi < cnt) {
                int slot = off + gi;
                float g = gates[slot];
                #pragma unroll
                for (int ni = 0; ni < 8; ni++) {
                    int col = nt * BN2 + ni * 16 + l15;
                    P[(size_t)slot * DM + col] = f2bf(g * acc[mi][ni][r]);
                }
            }
        }
    }
}

// ---------------- combine: y[t] = P[s0] + P[s1] (P bf16, pre-gated) ----------------
__global__ void combine_kernel(const unsigned short* __restrict__ P,
                               const int* __restrict__ slot_of, float* __restrict__ y) {
    int i = blockIdx.x * blockDim.x + threadIdx.x;    // per 8 elems
    int t = i / (DM / 8);
    int c8 = i % (DM / 8);
    int s0 = slot_of[t * 2], s1 = slot_of[t * 2 + 1];
    uint4 a = *(const uint4*)(P + (size_t)s0 * DM + c8 * 8);
    uint4 b = *(const uint4*)(P + (size_t)s1 * DM + c8 * 8);
    float o[8];
    const unsigned* aw = (const unsigned*)&a;
    const unsigned* bw = (const unsigned*)&b;
    #pragma unroll
    for (int j = 0; j < 4; j++) {
        union { unsigned u; float f; } al, ah, bl, bh;
        al.u = aw[j] << 16; ah.u = aw[j] & 0xffff0000u;
        bl.u = bw[j] << 16; bh.u = bw[j] & 0xffff0000u;
        o[j * 2]     = al.f + bl.f;
        o[j * 2 + 1] = ah.f + bh.f;
    }
    float4* yo = (float4*)(y + (size_t)t * DM + c8 * 8);
    yo[0] = make_float4(o[0], o[1], o[2], o[3]);
    yo[1] = make_float4(o[4], o[5], o[6], o[7]);
}

extern "C" void kernel_launch(void* const* d_in, const int* in_sizes, int n_in,
                              void* d_out, int out_size, void* d_ws, size_t ws_size,
                              hipStream_t stream) {
    (void)in_sizes; (void)n_in; (void)out_size; (void)ws_size;
    const float* x  = (const float*)d_in[0];
    const float* Wg = (const float*)d_in[1];
    const float* bg = (const float*)d_in[2];
    const float* W1 = (const float*)d_in[3];
    const float* W3 = (const float*)d_in[4];
    const float* W2 = (const float*)d_in[5];
    float* y = (float*)d_out;

    // carve order = R5's proven layout (xb at offset 0) — R9's reorder
    // coincided with gemm1 FETCH +4.7MB / +13us.
    char* p = (char*)d_ws;
    auto carve = [&](size_t bytes) -> char* {
        char* r = p;
        p += (bytes + 255) & ~(size_t)255;
        return r;
    };
    unsigned short* xb   = (unsigned short*)carve((size_t)TOKENS * DM * 2);
    unsigned short* w1t  = (unsigned short*)carve((size_t)NE * DM * HID * 2);   // 8 MB
    unsigned short* w3t  = (unsigned short*)carve((size_t)NE * DM * HID * 2);   // 8 MB (contiguous)
    unsigned short* w2t  = (unsigned short*)carve((size_t)NE * HID * DM * 2);
    unsigned short* Hb   = (unsigned short*)carve((size_t)NSLOT * HID * 2);
    int*   rows    = (int*)carve(NSLOT * 4);
    float* gates   = (float*)carve(NSLOT * 4);
    int*   slot_of = (int*)carve(NSLOT * 4);
    int*   tidx    = (int*)carve((size_t)TOKENS * 2 * 4);
    float* tp      = (float*)carve((size_t)TOKENS * 2 * 4);
    int*   counts  = (int*)carve(256);
    int*   offsets = (int*)carve(256);
    // P (bf16, 16 MB) aliases w1t+w3t (16 MB) — dead after gemm1 completes.
    unsigned short* P = w1t;

    prep_kernel<<<dim3(3072 + TOKENS / 4), dim3(256), 0, stream>>>(
        x, Wg, bg, W1, W3, W2, w1t, w3t, w2t, tidx, tp, xb);
    sortbuild_kernel<<<dim3(NB), dim3(256), 0, stream>>>(
        tidx, tp, counts, offsets, rows, gates, slot_of);
    gemm1_kernel<<<dim3((HID / BN) * MAXTILE), dim3(256), 0, stream>>>(xb, w1t, w3t, Hb, rows, counts, offsets);
    gemm2_kernel<<<dim3((DM / BN2) * MAXTILE), dim3(256), 0, stream>>>(Hb, w2t, P, gates, counts, offsets);
    combine_kernel<<<dim3((TOKENS * DM / 8) / 256), dim3(256), 0, stream>>>(P, slot_of, y);
}